// Round 10
// baseline (1082.469 us; speedup 1.0000x reference)
//
#include <hip/hip_runtime.h>

typedef unsigned short u16;
typedef float f32x4 __attribute__((ext_vector_type(4)));
typedef __bf16 bf16x8 __attribute__((ext_vector_type(8)));
typedef u16 u16x8 __attribute__((ext_vector_type(8)));

#define DEVFN __device__ __forceinline__

// B=8, S=256, V=32000, H=1024, HEADS=8, HD=128, N_HIGH=4, N_LOW=16, RATIO=4
// Block = 16 timesteps; 16 blocks. Row layout R(t,b) = (w*16 + o*4 + g)*8 + b.
// States stored per block-index: state[k] = state after block k-1 (state[0]=0).

DEVFN u16 f2bf(float f) {
  unsigned u = __builtin_bit_cast(unsigned, f);
  unsigned r = u + 0x7FFFu + ((u >> 16) & 1u);   // RNE
  return (u16)(r >> 16);
}

DEVFN bf16x8 cvt8(const float* p) {
  float4 f0 = *reinterpret_cast<const float4*>(p);
  float4 f1 = *reinterpret_cast<const float4*>(p + 4);
  u16x8 u;
  u[0] = f2bf(f0.x); u[1] = f2bf(f0.y); u[2] = f2bf(f0.z); u[3] = f2bf(f0.w);
  u[4] = f2bf(f1.x); u[5] = f2bf(f1.y); u[6] = f2bf(f1.z); u[7] = f2bf(f1.w);
  return __builtin_bit_cast(bf16x8, u);
}

DEVFN bf16x8 ldbf(const u16* p) { return *reinterpret_cast<const bf16x8*>(p); }
DEVFN float sigm(float x) { return 1.f / (1.f + expf(-x)); }

DEVFN void gload16(const u16* g, u16* l) {
  __builtin_amdgcn_global_load_lds(
      (const __attribute__((address_space(1))) void*)g,
      (__attribute__((address_space(3))) void*)l, 16, 0, 0);
}

// ============ 256x256 8-phase GEMM for the final projection ========================
__global__ __launch_bounds__(512) void gemm8(const u16* __restrict__ A,
                                             const u16* __restrict__ W,
                                             float* __restrict__ OUT) {
  __shared__ u16 sm[65536];                       // [buf 2][op 2][16384 elems]

  int nwg = gridDim.x;                            // 1000 (divisible by 8)
  int orig = blockIdx.x;
  int q = nwg >> 3;
  int xcd = orig & 7, idx = orig >> 3;
  int wg = xcd * q + idx;
  int m0 = (wg & 7) * 256;                        // m-fastest: W-panel per XCD
  int n0 = (wg >> 3) * 256;

  int tid = threadIdx.x;
  int wid = tid >> 6, lane = tid & 63;
  int wr = wid >> 2, wc = wid & 3;
  int lr = lane & 15;

  const u16* Abase = A + (size_t)m0 * 1024;
  const u16* Wbase = W + (size_t)n0 * 1024;

  int r0 = tid >> 3;                              // 0..63
  int c0 = ((tid & 7) ^ (r0 & 7)) << 3;           // pre-swizzled source col

  auto STAGE = [&](int half, int ktn, int tb) {   // half: 0=Ah0 1=Ah1 2=Bh0 3=Bh1
    int op = half >> 1, hh = half & 1;
    const u16* gb = op ? Wbase : Abase;
    u16* lp = sm + tb * 32768 + op * 16384 + hh * 8192;
    gload16(gb + (size_t)(hh * 128 + r0) * 1024 + ktn * 64 + c0, lp + tid * 8);
    gload16(gb + (size_t)(hh * 128 + 64 + r0) * 1024 + ktn * 64 + c0, lp + 4096 + tid * 8);
  };

  int aoff[8][2], boff[4][2];
#pragma unroll
  for (int mi = 0; mi < 8; ++mi)
#pragma unroll
    for (int kk = 0; kk < 2; ++kk) {
      int row = mi * 16 + lr;
      int colk = kk * 64 + ((lane >> 4) << 4);
      aoff[mi][kk] = wr * 16384 + row * 128 + (colk ^ ((row & 7) << 4));
    }
#pragma unroll
  for (int ni = 0; ni < 4; ++ni)
#pragma unroll
    for (int kk = 0; kk < 2; ++kk) {
      int rowb = (wc & 1) * 64 + ni * 16 + lr;
      int colk = kk * 64 + ((lane >> 4) << 4);
      boff[ni][kk] = 32768 + (wc >> 1) * 16384 + rowb * 128 +
                     (colk ^ ((rowb & 7) << 4));
    }
  const char* base = (const char*)sm;

  f32x4 acc[8][4];
#pragma unroll
  for (int mi = 0; mi < 8; ++mi)
#pragma unroll
    for (int ni = 0; ni < 4; ++ni) acc[mi][ni] = f32x4{0.f, 0.f, 0.f, 0.f};

  STAGE(0, 0, 0); STAGE(1, 0, 0); STAGE(2, 0, 0); STAGE(3, 0, 0);

  for (int kt = 0; kt < 16; ++kt) {
    int buf = kt & 1;
    int bb = buf * 65536;
    bf16x8 bfr[4][2];
#pragma unroll
    for (int p = 0; p < 4; ++p) {
      if (kt < 15) STAGE(p, kt + 1, buf ^ 1);
      if (p == 0) {
        if (kt < 15) asm volatile("s_waitcnt vmcnt(2)" ::: "memory");
        else         asm volatile("s_waitcnt vmcnt(0)" ::: "memory");
      }
      __builtin_amdgcn_s_barrier();
      asm volatile("" ::: "memory");
      if (p == 0) {
#pragma unroll
        for (int ni = 0; ni < 4; ++ni)
#pragma unroll
          for (int kk = 0; kk < 2; ++kk)
            bfr[ni][kk] = *(const bf16x8*)(base + bb + boff[ni][kk]);
      }
      bf16x8 af[2][2];
#pragma unroll
      for (int dm = 0; dm < 2; ++dm)
#pragma unroll
        for (int kk = 0; kk < 2; ++kk)
          af[dm][kk] = *(const bf16x8*)(base + bb + aoff[p * 2 + dm][kk]);
      __builtin_amdgcn_s_setprio(1);
#pragma unroll
      for (int dm = 0; dm < 2; ++dm)
#pragma unroll
        for (int ni = 0; ni < 4; ++ni)
#pragma unroll
          for (int kk = 0; kk < 2; ++kk)
            acc[p * 2 + dm][ni] = __builtin_amdgcn_mfma_f32_16x16x32_bf16(
                af[dm][kk], bfr[ni][kk], acc[p * 2 + dm][ni], 0, 0, 0);
      __builtin_amdgcn_s_setprio(0);
      __builtin_amdgcn_s_barrier();
      asm volatile("" ::: "memory");
    }
  }

  int rb = (lane >> 4) << 2;
#pragma unroll
  for (int mi = 0; mi < 8; ++mi)
#pragma unroll
    for (int ni = 0; ni < 4; ++ni)
#pragma unroll
      for (int rr = 0; rr < 4; ++rr) {
        size_t o = (size_t)(m0 + wr * 128 + mi * 16 + rb + rr) * 32000 +
                   (size_t)(n0 + wc * 64 + ni * 16 + lr);
        __builtin_nontemporal_store(acc[mi][ni][rr], &OUT[o]);
      }
}

// ============ LDS-staged 128x128 GEMM, BK=32, 3-stage counted-vmcnt pipeline =======
template<int NTSTORE, int OUTF, int BF16OUT, int CADD>
__global__ __launch_bounds__(256) void gemm_lds(
    const u16* __restrict__ A, const u16* __restrict__ W,
    const float* __restrict__ Cadd,
    float* __restrict__ OUT, u16* __restrict__ OUTbf,
    int ldo, int mtiles) {
  __shared__ u16 smA[3][128 * 32];
  __shared__ u16 smB[3][128 * 32];

  int nwg = gridDim.x;
  int orig = blockIdx.x;
  int q = nwg >> 3, r = nwg & 7;
  int xcd = orig & 7, idx = orig >> 3;
  int wg = (xcd < r ? xcd * (q + 1) : r * (q + 1) + (xcd - r) * q) + idx;
  int m0 = (wg % mtiles) * 128;
  int n0 = (wg / mtiles) * 128;

  int tid = threadIdx.x;
  int wv = tid >> 6, lane = tid & 63;
  int lrow = lane >> 2;
  int gcol = ((lane & 3) ^ ((lrow >> 1) & 3)) << 3;

  const u16* gA = A + (size_t)(m0 + wv * 32 + lrow) * 1024 + gcol;
  const u16* gB = W + (size_t)(n0 + wv * 32 + lrow) * 1024 + gcol;
  u16* lA0 = &smA[0][(wv * 32) * 32];
  u16* lA1 = &smA[0][(wv * 32 + 16) * 32];
  u16* lB0 = &smB[0][(wv * 32) * 32];
  u16* lB1 = &smB[0][(wv * 32 + 16) * 32];
  const int BUFO = 128 * 32;

  f32x4 acc[4][4];
#pragma unroll
  for (int mi = 0; mi < 4; ++mi)
#pragma unroll
    for (int ni = 0; ni < 4; ++ni) acc[mi][ni] = f32x4{0.f, 0.f, 0.f, 0.f};

  int qm = (wv >> 1) * 64, qn = (wv & 1) * 64;
  int lr = lane & 15;
  int kk = (lane >> 4) << 3;

  int offA[4], offB[4];
#pragma unroll
  for (int i = 0; i < 4; ++i) {
    int ra = qm + i * 16 + lr;
    offA[i] = ra * 64 + ((kk ^ (((ra >> 1) & 3) << 3)) << 1);
    int rbw = qn + i * 16 + lr;
    offB[i] = rbw * 64 + ((kk ^ (((rbw >> 1) & 3) << 3)) << 1);
  }
  const char* baseA = (const char*)&smA[0][0];
  const char* baseB = (const char*)&smB[0][0];

  gload16(gA, lA0);
  gload16(gA + 16 * 1024, lA1);
  gload16(gB, lB0);
  gload16(gB + 16 * 1024, lB1);
  gload16(gA + 32, lA0 + BUFO);
  gload16(gA + 16 * 1024 + 32, lA1 + BUFO);
  gload16(gB + 32, lB0 + BUFO);
  gload16(gB + 16 * 1024 + 32, lB1 + BUFO);

  for (int kt = 0; kt < 32; ++kt) {
    int buf = kt % 3;
    __builtin_amdgcn_sched_barrier(0);
    if (kt < 31) asm volatile("s_waitcnt vmcnt(4)" ::: "memory");
    else         asm volatile("s_waitcnt vmcnt(0)" ::: "memory");
    __builtin_amdgcn_s_barrier();
    asm volatile("" ::: "memory");
    if (kt < 30) {
      int k0 = (kt + 2) << 5;
      int bo = ((kt + 2) % 3) * BUFO;
      gload16(gA + k0, lA0 + bo);
      gload16(gA + 16 * 1024 + k0, lA1 + bo);
      gload16(gB + k0, lB0 + bo);
      gload16(gB + 16 * 1024 + k0, lB1 + bo);
    }
    int bb = buf * (BUFO * 2);
    bf16x8 av[4], bv[4];
#pragma unroll
    for (int i = 0; i < 4; ++i) {
      av[i] = *(const bf16x8*)(baseA + bb + offA[i]);
      bv[i] = *(const bf16x8*)(baseB + bb + offB[i]);
    }
#pragma unroll
    for (int mi = 0; mi < 4; ++mi)
#pragma unroll
      for (int ni = 0; ni < 4; ++ni)
        acc[mi][ni] = __builtin_amdgcn_mfma_f32_16x16x32_bf16(av[mi], bv[ni], acc[mi][ni], 0, 0, 0);
  }

  int rb = (lane >> 4) << 2;
#pragma unroll
  for (int mi = 0; mi < 4; ++mi)
#pragma unroll
    for (int ni = 0; ni < 4; ++ni)
#pragma unroll
      for (int rr = 0; rr < 4; ++rr) {
        int row = m0 + qm + mi * 16 + rb + rr;
        int col = n0 + qn + ni * 16 + lr;
        size_t o = (size_t)row * (size_t)ldo + col;
        float v = acc[mi][ni][rr];
        if constexpr (CADD) v += Cadd[o];
        if constexpr (OUTF) {
          if constexpr (NTSTORE) __builtin_nontemporal_store(v, &OUT[o]);
          else OUT[o] = v;
        }
        if constexpr (BF16OUT) OUTbf[o] = f2bf(v);
      }
}

// ---------------- generic GEMM (fallback, fp32-weight capable) ----------------------
template<int MT, int NT, int KW>
__global__ __launch_bounds__(64 * KW) void gemm2(
    const u16* __restrict__ A, int lda,
    const void* __restrict__ Wp, int ldw, int kwoff, int wbf,
    const float* __restrict__ Cadd, int ldc,
    float* __restrict__ OUT, u16* __restrict__ OUTbf, int ldo, int K) {
  int tid = threadIdx.x;
  int kw = tid >> 6;
  int lane = tid & 63;
  int lr = lane & 15;
  int kk = (lane >> 4) << 3;
  int n0 = blockIdx.x * (16 * NT);
  int m0 = blockIdx.y * (16 * MT);
  int KP = K / KW;
  int kb = kw * KP + kk;

  f32x4 acc[MT][NT];
#pragma unroll
  for (int mi = 0; mi < MT; ++mi)
#pragma unroll
    for (int ni = 0; ni < NT; ++ni) acc[mi][ni] = f32x4{0.f, 0.f, 0.f, 0.f};

  const u16* ap[MT];
#pragma unroll
  for (int mi = 0; mi < MT; ++mi) ap[mi] = A + (size_t)(m0 + mi * 16 + lr) * (size_t)lda + kb;

  if (wbf) {
    const u16* wb[NT];
#pragma unroll
    for (int ni = 0; ni < NT; ++ni)
      wb[ni] = (const u16*)Wp + (size_t)(n0 + ni * 16 + lr) * (size_t)ldw + kwoff + kb;
    for (int k0 = 0; k0 < KP; k0 += 32) {
      bf16x8 wv[NT];
#pragma unroll
      for (int ni = 0; ni < NT; ++ni) wv[ni] = ldbf(wb[ni] + k0);
#pragma unroll
      for (int mi = 0; mi < MT; ++mi) {
        bf16x8 a = ldbf(ap[mi] + k0);
#pragma unroll
        for (int ni = 0; ni < NT; ++ni)
          acc[mi][ni] = __builtin_amdgcn_mfma_f32_16x16x32_bf16(a, wv[ni], acc[mi][ni], 0, 0, 0);
      }
    }
  } else {
    const float* wf[NT];
#pragma unroll
    for (int ni = 0; ni < NT; ++ni)
      wf[ni] = (const float*)Wp + (size_t)(n0 + ni * 16 + lr) * (size_t)ldw + kwoff + kb;
    for (int k0 = 0; k0 < KP; k0 += 32) {
      bf16x8 wv[NT];
#pragma unroll
      for (int ni = 0; ni < NT; ++ni) wv[ni] = cvt8(wf[ni] + k0);
#pragma unroll
      for (int mi = 0; mi < MT; ++mi) {
        bf16x8 a = ldbf(ap[mi] + k0);
#pragma unroll
        for (int ni = 0; ni < NT; ++ni)
          acc[mi][ni] = __builtin_amdgcn_mfma_f32_16x16x32_bf16(a, wv[ni], acc[mi][ni], 0, 0, 0);
      }
    }
  }

  if constexpr (KW > 1) {
    __shared__ f32x4 red[KW][MT * NT][64];
#pragma unroll
    for (int mi = 0; mi < MT; ++mi)
#pragma unroll
      for (int ni = 0; ni < NT; ++ni) red[kw][mi * NT + ni][lane] = acc[mi][ni];
    __syncthreads();
    if (kw) return;
    for (int w2 = 1; w2 < KW; ++w2)
#pragma unroll
      for (int mi = 0; mi < MT; ++mi)
#pragma unroll
        for (int ni = 0; ni < NT; ++ni) acc[mi][ni] += red[w2][mi * NT + ni][lane];
  }

  int rb = (lane >> 4) << 2;
#pragma unroll
  for (int mi = 0; mi < MT; ++mi)
#pragma unroll
    for (int ni = 0; ni < NT; ++ni)
#pragma unroll
      for (int rr = 0; rr < 4; ++rr) {
        int row = m0 + mi * 16 + rb + rr;
        int col = n0 + ni * 16 + lr;
        size_t o = (size_t)row * (size_t)ldo + col;
        float v = acc[mi][ni][rr];
        if (Cadd) v += Cadd[(size_t)row * (size_t)ldc + col];
        if (OUT) OUT[o] = v;
        if (OUTbf) OUTbf[o] = f2bf(v);
      }
}

// ---------------- GRU layer-step body: 512 thr, 8-way K-split, 16 rows/tile ---------
// Rationale: chain dispatches were 8 waves/CU (latency-exposed). KW=8 + MT=1 doubles
// waves per block and halves per-wave work -> 16-32 waves/CU of TLP.
DEVFN void gru_step_body(const u16* __restrict__ X, const u16* __restrict__ Hb,
                         const float* __restrict__ Hf,
                         const u16* __restrict__ Wih, const u16* __restrict__ Whh,
                         const float* __restrict__ bih, const float* __restrict__ bhh,
                         const float* __restrict__ gx,
                         float* __restrict__ Hof, u16* __restrict__ Hob,
                         u16* __restrict__ hist,
                         int m0, int j0, int kw, int lane,
                         f32x4 (*red)[4][64]) {
  int lr = lane & 15;
  int kk = (lane >> 4) << 3;
  const int KP = 128;
  int kb = kw * KP + kk;

  f32x4 aR = f32x4{0.f, 0.f, 0.f, 0.f};
  f32x4 aZ = f32x4{0.f, 0.f, 0.f, 0.f};
  f32x4 aNX = f32x4{0.f, 0.f, 0.f, 0.f};
  f32x4 aNH = f32x4{0.f, 0.f, 0.f, 0.f};

  const u16* hp = Hb + (size_t)(m0 + lr) * 1024 + kb;
  size_t wro = (size_t)(j0 + lr) * 1024 + kb;
  const u16 *phr = Whh + wro, *phz = Whh + wro + 1048576, *phn = Whh + wro + 2097152;

  if (gx) {
    // slim: only H@Whh (x-part precomputed in gx)
#pragma unroll
    for (int k0 = 0; k0 < KP; k0 += 32) {
      bf16x8 whr = ldbf(phr + k0), whz = ldbf(phz + k0), whn = ldbf(phn + k0);
      bf16x8 ah = ldbf(hp + k0);
      aR = __builtin_amdgcn_mfma_f32_16x16x32_bf16(ah, whr, aR, 0, 0, 0);
      aZ = __builtin_amdgcn_mfma_f32_16x16x32_bf16(ah, whz, aZ, 0, 0, 0);
      aNH = __builtin_amdgcn_mfma_f32_16x16x32_bf16(ah, whn, aNH, 0, 0, 0);
    }
  } else {
    const u16* xp = X + (size_t)(m0 + lr) * 1024 + kb;
    const u16 *pxr = Wih + wro, *pxz = Wih + wro + 1048576, *pxn = Wih + wro + 2097152;
#pragma unroll
    for (int k0 = 0; k0 < KP; k0 += 32) {
      bf16x8 wxr = ldbf(pxr + k0), wxz = ldbf(pxz + k0), wxn = ldbf(pxn + k0);
      bf16x8 whr = ldbf(phr + k0), whz = ldbf(phz + k0), whn = ldbf(phn + k0);
      bf16x8 ax = ldbf(xp + k0);
      bf16x8 ah = ldbf(hp + k0);
      aR = __builtin_amdgcn_mfma_f32_16x16x32_bf16(ax, wxr, aR, 0, 0, 0);
      aR = __builtin_amdgcn_mfma_f32_16x16x32_bf16(ah, whr, aR, 0, 0, 0);
      aZ = __builtin_amdgcn_mfma_f32_16x16x32_bf16(ax, wxz, aZ, 0, 0, 0);
      aZ = __builtin_amdgcn_mfma_f32_16x16x32_bf16(ah, whz, aZ, 0, 0, 0);
      aNX = __builtin_amdgcn_mfma_f32_16x16x32_bf16(ax, wxn, aNX, 0, 0, 0);
      aNH = __builtin_amdgcn_mfma_f32_16x16x32_bf16(ah, whn, aNH, 0, 0, 0);
    }
  }

  red[kw][0][lane] = aR;
  red[kw][1][lane] = aZ;
  red[kw][2][lane] = aNX;
  red[kw][3][lane] = aNH;
  __syncthreads();
  if (kw == 0) {
    for (int w2 = 1; w2 < 8; ++w2) {
      aR += red[w2][0][lane];
      aZ += red[w2][1][lane];
      aNX += red[w2][2][lane];
      aNH += red[w2][3][lane];
    }
    int c = j0 + lr;
    float br = bih[c] + bhh[c];
    float bz = bih[1024 + c] + bhh[1024 + c];
    float bnx = bih[2048 + c];
    float bnh = bhh[2048 + c];
    int rb2 = (lane >> 4) << 2;
#pragma unroll
    for (int rr = 0; rr < 4; ++rr) {
      int row = m0 + rb2 + rr;
      float gr = 0.f, gz = 0.f, gn = 0.f;
      if (gx) {
        const float* gp = gx + (size_t)row * 3072;
        gr = gp[c]; gz = gp[1024 + c]; gn = gp[2048 + c];
      }
      float r = sigm(gr + aR[rr] + br);
      float z = sigm(gz + aZ[rr] + bz);
      float n = tanhf(gn + aNX[rr] + bnx + r * (aNH[rr] + bnh));
      size_t o = (size_t)row * 1024 + c;
      float hv = (1.f - z) * n + z * Hf[o];
      Hof[o] = hv;
      u16 hb = f2bf(hv);
      Hob[o] = hb;
      if (hist) hist[o] = hb;
    }
  }
}

// ---------------- dual GRU layer + folded fp32->bf16 weight conversion --------------
struct GruP {
  const u16* X; const u16* Hb; const float* Hf;
  const u16* Wbih; const u16* Wbhh;
  const float* Wfih; const float* Wfhh;
  const float* bih; const float* bhh;
  const float* gx;
  float* Hof; u16* Hob; u16* hist;
};
struct FoldSeg { const float* src; u16* dst; };
struct FoldArgs { FoldSeg s[7]; long long pref[8]; long long base; long long total; int nseg; };

__global__ __launch_bounds__(512) void gru_dual(GruP pa, GruP pb, int tiles1,
                                                int tiles_total, int wbf, FoldArgs fa) {
  int yy = (int)blockIdx.y;
  if (yy >= tiles_total) {
    // folded flat weight conversion (idempotent chunks of 4096 elems)
    if (fa.total == 0) return;
    long long L = (long long)(yy - tiles_total) * gridDim.x + blockIdx.x;
    long long off = fa.base + L * 4096;
    if (off >= fa.total) return;
    int s = 0;
    while (off >= fa.pref[s + 1]) ++s;
    long long local = off - fa.pref[s] + ((long long)threadIdx.x << 3);
    *reinterpret_cast<u16x8*>(fa.s[s].dst + local) =
        __builtin_bit_cast(u16x8, cvt8(fa.s[s].src + local));
    return;
  }

  GruP p; int m0;
  if (yy < tiles1) { p = pa; m0 = yy * 16; }
  else { p = pb; m0 = (yy - tiles1) * 16; }
  int tid = threadIdx.x;
  int kw = tid >> 6;                 // 0..7
  int lane = tid & 63;
  __shared__ f32x4 red[8][4][64];
  int j0 = blockIdx.x * 16;

  if (wbf) {
    gru_step_body(p.X, p.Hb, p.Hf, p.Wbih, p.Wbhh, p.bih, p.bhh, p.gx,
                  p.Hof, p.Hob, p.hist, m0, j0, kw, lane, red);
    return;
  }

  // fp32-weight fallback path (full gates; gx is null when !packW)
  int lr = lane & 15;
  int kk = (lane >> 4) << 3;
  const int KP = 128;
  int kb = kw * KP + kk;
  f32x4 aR = f32x4{0.f, 0.f, 0.f, 0.f};
  f32x4 aZ = f32x4{0.f, 0.f, 0.f, 0.f};
  f32x4 aNX = f32x4{0.f, 0.f, 0.f, 0.f};
  f32x4 aNH = f32x4{0.f, 0.f, 0.f, 0.f};
  const u16* xp = p.X + (size_t)(m0 + lr) * 1024 + kb;
  const u16* hp = p.Hb + (size_t)(m0 + lr) * 1024 + kb;
  size_t wro = (size_t)(j0 + lr) * 1024 + kb;
  const float *pxr = p.Wfih + wro, *pxz = p.Wfih + wro + 1048576, *pxn = p.Wfih + wro + 2097152;
  const float *phr = p.Wfhh + wro, *phz = p.Wfhh + wro + 1048576, *phn = p.Wfhh + wro + 2097152;
  for (int k0 = 0; k0 < KP; k0 += 32) {
    bf16x8 wxr = cvt8(pxr + k0), wxz = cvt8(pxz + k0), wxn = cvt8(pxn + k0);
    bf16x8 whr = cvt8(phr + k0), whz = cvt8(phz + k0), whn = cvt8(phn + k0);
    bf16x8 ax = ldbf(xp + k0);
    bf16x8 ah = ldbf(hp + k0);
    aR = __builtin_amdgcn_mfma_f32_16x16x32_bf16(ax, wxr, aR, 0, 0, 0);
    aR = __builtin_amdgcn_mfma_f32_16x16x32_bf16(ah, whr, aR, 0, 0, 0);
    aZ = __builtin_amdgcn_mfma_f32_16x16x32_bf16(ax, wxz, aZ, 0, 0, 0);
    aZ = __builtin_amdgcn_mfma_f32_16x16x32_bf16(ah, whz, aZ, 0, 0, 0);
    aNX = __builtin_amdgcn_mfma_f32_16x16x32_bf16(ax, wxn, aNX, 0, 0, 0);
    aNH = __builtin_amdgcn_mfma_f32_16x16x32_bf16(ah, whn, aNH, 0, 0, 0);
  }
  red[kw][0][lane] = aR;
  red[kw][1][lane] = aZ;
  red[kw][2][lane] = aNX;
  red[kw][3][lane] = aNH;
  __syncthreads();
  if (kw) return;
  for (int w2 = 1; w2 < 8; ++w2) {
    aR += red[w2][0][lane];
    aZ += red[w2][1][lane];
    aNX += red[w2][2][lane];
    aNH += red[w2][3][lane];
  }
  int c = j0 + lr;
  float br = p.bih[c] + p.bhh[c];
  float bz = p.bih[1024 + c] + p.bhh[1024 + c];
  float bnx = p.bih[2048 + c];
  float bnh = p.bhh[2048 + c];
  int rb2 = (lane >> 4) << 2;
#pragma unroll
  for (int rr = 0; rr < 4; ++rr) {
    int row = m0 + rb2 + rr;
    float r = sigm(aR[rr] + br);
    float z = sigm(aZ[rr] + bz);
    float n = tanhf(aNX[rr] + bnx + r * (aNH[rr] + bnh));
    size_t o = (size_t)row * 1024 + c;
    float hv = (1.f - z) * n + z * p.Hf[o];
    p.Hof[o] = hv;
    u16 hb = f2bf(hv);
    p.Hob[o] = hb;
    if (p.hist) p.hist[o] = hb;
  }
}

// ---------------- final projection fallback (fp32 W, direct) ------------------------
__global__ __launch_bounds__(256) void gemm_big(const u16* __restrict__ A,
                                                const void* __restrict__ Wp, int wbf,
                                                float* __restrict__ OUT) {
  int wv = threadIdx.x >> 6;
  int lane = threadIdx.x & 63;
  int lr = lane & 15;
  int kk = (lane >> 4) << 3;
  int m0 = blockIdx.x * 256 + wv * 64;
  int n0 = blockIdx.y * 64;

  f32x4 acc[4][4];
#pragma unroll
  for (int mi = 0; mi < 4; ++mi)
#pragma unroll
    for (int ni = 0; ni < 4; ++ni) acc[mi][ni] = f32x4{0.f, 0.f, 0.f, 0.f};

  const u16* ap[4];
#pragma unroll
  for (int mi = 0; mi < 4; ++mi) ap[mi] = A + (size_t)(m0 + mi * 16 + lr) * 1024 + kk;

  const float* wf[4];
#pragma unroll
  for (int ni = 0; ni < 4; ++ni) wf[ni] = (const float*)Wp + (size_t)(n0 + ni * 16 + lr) * 1024 + kk;
  for (int k0 = 0; k0 < 1024; k0 += 32) {
    bf16x8 wvv[4];
#pragma unroll
    for (int ni = 0; ni < 4; ++ni) wvv[ni] = cvt8(wf[ni] + k0);
#pragma unroll
    for (int mi = 0; mi < 4; ++mi) {
      bf16x8 a = ldbf(ap[mi] + k0);
#pragma unroll
      for (int ni = 0; ni < 4; ++ni)
        acc[mi][ni] = __builtin_amdgcn_mfma_f32_16x16x32_bf16(a, wvv[ni], acc[mi][ni], 0, 0, 0);
    }
  }

  int rb = (lane >> 4) << 2;
#pragma unroll
  for (int mi = 0; mi < 4; ++mi)
#pragma unroll
    for (int ni = 0; ni < 4; ++ni)
#pragma unroll
      for (int rr = 0; rr < 4; ++rr) {
        size_t o = (size_t)(m0 + mi * 16 + rb + rr) * 32000 + (size_t)(n0 + ni * 16 + lr);
        __builtin_nontemporal_store(acc[mi][ni][rr], &OUT[o]);
      }
}

// ---------------- fused fp32 -> bf16 weight pack (strided-capable, serial) ----------
struct CvtSeg { const float* src; u16* dst; int src_ld; int col_off; int log2c; int nblk; };
struct CvtArgs { CvtSeg seg[11]; int nseg; };

__global__ void cvt_all(CvtArgs a) {
  int blk = blockIdx.x;
  int s = 0;
  while (s < a.nseg - 1 && blk >= a.seg[s].nblk) { blk -= a.seg[s].nblk; ++s; }
  const CvtSeg g = a.seg[s];
  size_t idx = ((size_t)blk * 256 + threadIdx.x) * 8;
  size_t row = idx >> g.log2c;
  int col = (int)(idx & ((1u << g.log2c) - 1));
  const float* sp = g.src + row * (size_t)g.src_ld + g.col_off + col;
  *reinterpret_cast<u16x8*>(g.dst + idx) = __builtin_bit_cast(u16x8, cvt8(sp));
}

// ---------------- single-dispatch state zeroing -------------------------------------
struct ZeroArgs { unsigned* p[8]; long long pref[9]; };
__global__ void zero8(ZeroArgs z) {
  long long i = (long long)blockIdx.x * 256 + threadIdx.x;
  if (i >= z.pref[8]) return;
  int s = 0;
  while (i >= z.pref[s + 1]) ++s;
  z.p[s][i - z.pref[s]] = 0u;
}

// ---------------- embeds (bf16) + compact high-row copy -----------------------------
__global__ void embed_kernel(const int* __restrict__ ids, const float* __restrict__ emb,
                             const float* __restrict__ pos, u16* __restrict__ out,
                             u16* __restrict__ hiX) {
  int idx = blockIdx.x * 256 + threadIdx.x;
  int e8 = (idx & 127) << 3;
  int rb = idx >> 7;
  int t = rb >> 3, b = rb & 7;
  int w = t >> 4, lsp = t & 15, g = lsp >> 2, o = lsp & 3;
  int R = ((w << 4) + (o << 2) + g) * 8 + b;
  int tok = ids[b * 256 + t];
  const float* ep = emb + (size_t)tok * 1024 + e8;
  const float* pp = pos + (size_t)t * 1024 + e8;
  u16x8 u;
#pragma unroll
  for (int i = 0; i < 8; ++i) u[i] = f2bf(ep[i] + pp[i]);
  *reinterpret_cast<u16x8*>(out + (size_t)R * 1024 + e8) = u;
  if (o == 0)
    *reinterpret_cast<u16x8*>(hiX + (size_t)(w * 32 + g * 8 + b) * 1024 + e8) = u;
}

// ---------------- batched inp = gelu(einp + hc + bin) -------------------------------
__global__ void inp_all(const float* __restrict__ einp, const float* __restrict__ kvhAll,
                        const float* __restrict__ bin, float* __restrict__ inpb,
                        u16* __restrict__ inpbf) {
  int idx = blockIdx.x * 256 + threadIdx.x;
  int r = idx >> 10, j = idx & 1023;
  int w = r >> 7, r7 = r & 127;
  int g = (r7 >> 3) & 3, b = r7 & 7;
  float x = einp[idx] + kvhAll[(size_t)(w * 32 + g * 8 + b) * 3072 + 2048 + j] + bin[j];
  float t = tanhf(0.7978845608028654f * (x + 0.044715f * x * x * x));
  float v = 0.5f * x * (1.f + t);
  inpb[idx] = v;
  inpbf[idx] = f2bf(v);
}

// ---------------- batched attention -------------------------------------------------
__global__ void attn_all(const float* __restrict__ qb, const float* __restrict__ kvhAll,
                         u16* __restrict__ ctxbf) {
  int r = blockIdx.x;
  int w = r >> 7, r7 = r & 127;
  int sp = r7 >> 3;
  int g = sp & 3;
  int b = r7 & 7;
  int lane = threadIdx.x;
  const float* kvb = kvhAll + (size_t)w * 32 * 3072;
  __shared__ float aw[8][4];
  if (lane < 32) {
    int head = lane >> 2, t = lane & 3;
    float s = 0.f;
    if (t <= g) {
      const float* qp = qb + (size_t)r * 1024 + head * 128;
      const float* kp = kvb + (size_t)(t * 8 + b) * 3072 + head * 128;
      for (int d = 0; d < 128; ++d) s += qp[d] * kp[d];
      s *= 0.08838834764831845f;
    }
    float sc[4];
    sc[0] = __shfl(s, (head << 2) + 0);
    sc[1] = __shfl(s, (head << 2) + 1);
    sc[2] = __shfl(s, (head << 2) + 2);
    sc[3] = __shfl(s, (head << 2) + 3);
    if (t == 0) {
      float mx = -1e30f;
      for (int u = 0; u <= g; ++u) mx = fmaxf(mx, sc[u]);
      float p[4] = {0.f, 0.f, 0.f, 0.f};
      float den = 0.f;
      for (int u = 0; u <= g; ++u) { p[u] = expf(sc[u] - mx); den += p[u]; }
      float inv = 1.f / den;
      for (int u = 0; u < 4; ++u) aw[head][u] = (u <= g) ? p[u] * inv : 0.f;
    }
  }
  __syncthreads();
  for (int idx = lane; idx < 1024; idx += 64) {
    int head = idx >> 7;
    float acc = 0.f;
#pragma unroll
    for (int t = 0; t < 4; ++t) acc += aw[head][t] * kvb[(size_t)(t * 8 + b) * 3072 + 1024 + idx];
    ctxbf[(size_t)r * 1024 + idx] = f2bf(acc);
  }
}

// ---------------- batched layernorm -> bf16 Y ---------------------------------------
__global__ void ln_all(const float* __restrict__ ls1f, const float* __restrict__ g_,
                       const float* __restrict__ b_, u16* __restrict__ Ybf) {
  int bid = blockIdx.x;
  int w = bid >> 7, r7 = bid & 127;
  int tid = threadIdx.x;
  const float* x = ls1f + (size_t)(w + 1) * 131072 + (size_t)r7 * 1024;
  float s = 0.f, s2 = 0.f;
  for (int j = tid; j < 1024; j += 256) { float v = x[j]; s += v; s2 += v * v; }
  for (int off = 32; off; off >>= 1) { s += __shfl_xor(s, off); s2 += __shfl_xor(s2, off); }
  __shared__ float rs[4], rs2[4], mv[2];
  int wv = tid >> 6;
  if ((tid & 63) == 0) { rs[wv] = s; rs2[wv] = s2; }
  __syncthreads();
  if (tid == 0) {
    float S = rs[0] + rs[1] + rs[2] + rs[3];
    float S2 = rs2[0] + rs2[1] + rs2[2] + rs2[3];
    float mu = S * (1.f / 1024.f);
    float var = S2 * (1.f / 1024.f) - mu * mu;
    mv[0] = mu;
    mv[1] = rsqrtf(var + 1e-5f);
  }
  __syncthreads();
  float mu = mv[0], rstd = mv[1];
  int sp = r7 >> 3, b = r7 & 7;
  int g = sp & 3, o = sp >> 2;
  int t = w * 16 + g * 4 + o;
  u16* yrow = Ybf + (size_t)(b * 256 + t) * 1024;
  for (int j = tid; j < 1024; j += 256) {
    float v = (x[j] - mu) * rstd * g_[j] + b_[j];
    yrow[j] = f2bf(v);
  }
}

extern "C" void kernel_launch(void* const* d_in, const int* in_sizes, int n_in,
                              void* d_out, int out_size, void* d_ws, size_t ws_size,
                              hipStream_t stream) {
  const int* ids = (const int*)d_in[0];
  const float* emb = (const float*)d_in[1];
  const float* pos = (const float*)d_in[2];
  const float* Wih_h = (const float*)d_in[3];
  const float* bih_h = (const float*)d_in[4];
  const float* Whh_h = (const float*)d_in[5];
  const float* bhh_h = (const float*)d_in[6];
  const float* Win = (const float*)d_in[7];
  const float* bin_ = (const float*)d_in[8];
  const float* Wq = (const float*)d_in[9];
  const float* Wk = (const float*)d_in[10];
  const float* Wv = (const float*)d_in[11];
  const float* Wo = (const float*)d_in[12];
  const float* Wih_l = (const float*)d_in[13];
  const float* bih_l = (const float*)d_in[14];
  const float* Whh_l = (const float*)d_in[15];
  const float* bhh_l = (const float*)d_in[16];
  const float* ln_g = (const float*)d_in[17];
  const float* ln_b = (const float*)d_in[18];
  const float* Wout = (const float*)d_in[19];
  float* out = (float*)d_out;

  size_t off = 0;
  char* wsb = (char*)d_ws;
  auto allocF = [&](size_t n) { float* p = (float*)(wsb + off); off += n * 4; return p; };
  auto allocU = [&](size_t n) { u16* p = (u16*)(wsb + off); off += n * 2; return p; };

  float* hs0f = allocF((size_t)17 * 32768);
  float* hs1f = allocF((size_t)17 * 32768);
  float* ls0f = allocF((size_t)17 * 131072);
  float* ls1f = allocF((size_t)17 * 131072);
  u16* hs0b = allocU((size_t)17 * 32768);
  u16* hs1b = allocU((size_t)17 * 32768);
  u16* ls0b = allocU((size_t)17 * 131072);
  u16* ls1b = allocU((size_t)17 * 131072);
  u16* histAll = allocU(524288);
  u16* embB = allocU(2097152);
  u16* hiX = allocU(524288);              // [512][1024] compact high rows
  float* einp = allocF(2097152);
  float* kvhAll = allocF((size_t)512 * 3072);
  float* inpb = allocF(2097152);
  u16* inpbf = allocU(2097152);
  float* qb = allocF(2097152);
  u16* ctxbf = allocU(2097152);
  u16* x2bf = allocU(2097152);
  u16* Ybf = allocU(2097152);
  float* GXH = allocF((size_t)512 * 3072);    // high l0 x-gates
  float* GXL = allocF((size_t)2048 * 3072);   // low l0 x-gates

  const size_t WPACK_BYTES = (size_t)(4 * 6291456 + 1048576 + 1048576 + 1048576 + 3145728) * 2;
  bool packW = (off + WPACK_BYTES <= ws_size);
  u16 *WihHb = nullptr, *WhhHb = nullptr, *WihLb = nullptr, *WhhLb = nullptr;
  u16 *WinB0 = nullptr, *WqB = nullptr, *WoB = nullptr, *KVp = nullptr;
  if (packW) {
    WihHb = allocU(6291456);
    WhhHb = allocU(6291456);
    WihLb = allocU(6291456);
    WhhLb = allocU(6291456);
    WinB0 = allocU(1048576);
    WqB = allocU(1048576);
    WoB = allocU(1048576);
    KVp = allocU(3145728);
  }
  bool packWout = packW && (off + (size_t)32768000 * 2 <= ws_size);
  u16* WoutB = nullptr;
  if (packWout) WoutB = allocU(32768000);

  // ---- single-dispatch zero of all 8 state slice-0 regions ----
  {
    ZeroArgs z;
    long long pf = 0;
    int si = 0;
    auto addZ = [&](void* p, long long words) {
      z.p[si] = (unsigned*)p; z.pref[si] = pf; pf += words; ++si;
    };
    addZ(hs0f, 32768); addZ(hs1f, 32768); addZ(ls0f, 131072); addZ(ls1f, 131072);
    addZ(hs0b, 16384); addZ(hs1b, 16384); addZ(ls0b, 65536); addZ(ls1b, 65536);
    z.pref[8] = pf;     // 491520 words
    zero8<<<(int)((pf + 255) / 256), 256, 0, stream>>>(z);
  }

  // ---- prologue ----
  embed_kernel<<<1024, 256, 0, stream>>>(ids, emb, pos, embB, hiX);
  if (packW) {
    CvtArgs ca{};
    int ns = 0, tot = 0;
    auto add = [&](const float* s, u16* d, int ld, int co, int l2c, size_t nelem) {
      int nb = (int)(nelem / 2048);
      ca.seg[ns++] = CvtSeg{s, d, ld, co, l2c, nb};
      tot += nb;
    };
    add(Wih_h, WihHb, 1024, 0, 10, 6291456);
    add(Whh_h, WhhHb, 1024, 0, 10, 6291456);
    add(Win, WinB0, 2048, 0, 10, 1048576);
    add(Win, KVp + 2097152, 2048, 1024, 10, 1048576);
    ca.nseg = ns;
    cvt_all<<<tot, 256, 0, stream>>>(ca);
  }
  int wbfW = packW ? 1 : 0;

  // folded flat conversions distributed across the 17 high-chain dispatches
  FoldArgs fa{};
  fa.total = 0;
  FoldArgs fz{};
  fz.total = 0;
  long long bpd = 0;
  int extraY = 0;
  if (packW) {
    int ns = 0;
    long long pref = 0;
    auto addF = [&](const float* s, u16* d, long long n) {
      fa.s[ns].src = s; fa.s[ns].dst = d; fa.pref[ns] = pref; pref += n; ++ns;
    };
    addF(Wih_l, WihLb, 6291456);
    addF(Whh_l, WhhLb, 6291456);
    addF(Wq, WqB, 1048576);
    addF(Wo, WoB, 1048576);
    addF(Wk, KVp, 1048576);
    addF(Wv, KVp + 1048576, 1048576);
    if (packWout) addF(Wout, WoutB, 32768000);
    fa.pref[ns] = pref;
    fa.total = pref;
    fa.nseg = ns;
    long long tb = pref / 4096;           // 4096-elem chunks (512 thr x 8)
    bpd = (tb + 16) / 17;
    extraY = (int)((bpd + 63) / 64);
  }

  // einp + high l0 x-gates (batched)
  if (packW) {
    gemm_lds<0, 1, 0, 0><<<128, 256, 0, stream>>>(embB, WinB0, nullptr, einp, nullptr, 1024, 16);
    gemm_lds<0, 1, 0, 0><<<96, 256, 0, stream>>>(hiX, WihHb, nullptr, GXH, nullptr, 3072, 4);
  } else {
    gemm2<2, 2, 2><<<dim3(32, 64), 128, 0, stream>>>(
        embB, 1024, Win, 2048, 0, 0, nullptr, 0, einp, nullptr, 1024, 1024);
  }

  const size_t LW = (size_t)3072 * 1024;
  auto HP = [&](int layer, int w) {
    GruP p;
    if (layer == 0) {
      p.X = embB + (size_t)w * 131072;
      p.Hb = hs0b + (size_t)w * 32768; p.Hf = hs0f + (size_t)w * 32768;
      p.Wbih = WihHb; p.Wbhh = WhhHb; p.Wfih = Wih_h; p.Wfhh = Whh_h;
      p.bih = bih_h; p.bhh = bhh_h;
      p.gx = packW ? (GXH + (size_t)w * 32 * 3072) : nullptr;
      p.Hof = hs0f + (size_t)(w + 1) * 32768; p.Hob = hs0b + (size_t)(w + 1) * 32768;
      p.hist = nullptr;
    } else {
      p.X = hs0b + (size_t)(w + 1) * 32768;
      p.Hb = hs1b + (size_t)w * 32768; p.Hf = hs1f + (size_t)w * 32768;
      p.Wbih = WihHb ? WihHb + LW : nullptr; p.Wbhh = WhhHb ? WhhHb + LW : nullptr;
      p.Wfih = Wih_h + LW; p.Wfhh = Whh_h + LW;
      p.bih = bih_h + 3072; p.bhh = bhh_h + 3072;
      p.gx = nullptr;
      p.Hof = hs1f + (size_t)(w + 1) * 32768; p.Hob = hs1b + (size_t)(w + 1) * 32768;
      p.hist = histAll + (size_t)w * 32768;
    }
    return p;
  };
  auto LP = [&](int layer, int w) {
    GruP p;
    if (layer == 0) {
      p.X = x2bf + (size_t)w * 131072;
      p.Hb = ls0b + (size_t)w * 131072; p.Hf = ls0f + (size_t)w * 131072;
      p.Wbih = WihLb; p.Wbhh = WhhLb; p.Wfih = Wih_l; p.Wfhh = Whh_l;
      p.bih = bih_l; p.bhh = bhh_l;
      p.gx = packW ? (GXL + (size_t)w * 128 * 3072) : nullptr;
      p.Hof = ls0f + (size_t)(w + 1) * 131072; p.Hob = ls0b + (size_t)(w + 1) * 131072;
      p.hist = nullptr;
    } else {
      p.X = ls0b + (size_t)(w + 1) * 131072;
      p.Hb = ls1b + (size_t)w * 131072; p.Hf = ls1f + (size_t)w * 131072;
      p.Wbih = WihLb ? WihLb + LW : nullptr; p.Wbhh = WhhLb ? WhhLb + LW : nullptr;
      p.Wfih = Wih_l + LW; p.Wfhh = Whh_l + LW;
      p.bih = bih_l + 3072; p.bhh = bhh_l + 3072;
      p.gx = nullptr;
      p.Hof = ls1f + (size_t)(w + 1) * 131072; p.Hob = ls1b + (size_t)(w + 1) * 131072;
      p.hist = nullptr;
    }
    return p;
  };

  // ---- high chain: 17 dispatches (16-row tiles; +folded cvt on idle CUs) ----
  auto launch_high = [&](GruP pa, GruP pb, int t1, int ttot, int d) {
    if (packW && fa.total) {
      fa.base = (long long)d * bpd * 4096;
      gru_dual<<<dim3(64, ttot + extraY), 512, 0, stream>>>(pa, pb, t1, ttot, wbfW, fa);
    } else {
      gru_dual<<<dim3(64, ttot), 512, 0, stream>>>(pa, pb, t1, ttot, wbfW, fz);
    }
  };
  launch_high(HP(0, 0), HP(0, 0), 2, 2, 0);
  for (int d = 1; d <= 15; ++d) launch_high(HP(1, d - 1), HP(0, d), 2, 4, d);
  launch_high(HP(1, 15), HP(1, 15), 2, 2, 16);

  // ---- batched mid-section ----
  if (packW) {
    gemm_lds<0, 1, 0, 0><<<96, 256, 0, stream>>>(histAll, KVp, nullptr, kvhAll, nullptr, 3072, 4);
  } else {
    gemm2<2, 2, 2><<<dim3(32, 16), 128, 0, stream>>>(
        histAll, 1024, Wk, 1024, 0, 0, nullptr, 0, kvhAll, nullptr, 3072, 1024);
    gemm2<2, 2, 2><<<dim3(32, 16), 128, 0, stream>>>(
        histAll, 1024, Wv, 1024, 0, 0, nullptr, 0, kvhAll + 1024, nullptr, 3072, 1024);
    gemm2<2, 2, 2><<<dim3(32, 16), 128, 0, stream>>>(
        histAll, 1024, Win, 2048, 1024, 0, nullptr, 0, kvhAll + 2048, nullptr, 3072, 1024);
  }
  inp_all<<<8192, 256, 0, stream>>>(einp, kvhAll, bin_, inpb, inpbf);
  if (packW)
    gemm_lds<0, 1, 0, 0><<<128, 256, 0, stream>>>(inpbf, WqB, nullptr, qb, nullptr, 1024, 16);
  else
    gemm2<2, 2, 2><<<dim3(32, 64), 128, 0, stream>>>(
        inpbf, 1024, Wq, 1024, 0, 0, nullptr, 0, qb, nullptr, 1024, 1024);
  attn_all<<<2048, 64, 0, stream>>>(qb, kvhAll, ctxbf);
  if (packW) {
    gemm_lds<0, 0, 1, 1><<<128, 256, 0, stream>>>(ctxbf, WoB, inpb, nullptr, x2bf, 1024, 16);
    gemm_lds<0, 1, 0, 0><<<384, 256, 0, stream>>>(x2bf, WihLb, nullptr, GXL, nullptr, 3072, 16);
  } else {
    gemm2<2, 2, 2><<<dim3(32, 64), 128, 0, stream>>>(
        ctxbf, 1024, Wo, 1024, 0, 0, inpb, 1024, nullptr, x2bf, 1024, 1024);
  }

  // ---- low chain: 17 dispatches (16-row tiles: 8 per problem) ----
  gru_dual<<<dim3(64, 8), 512, 0, stream>>>(LP(0, 0), LP(0, 0), 8, 8, wbfW, fz);
  for (int d = 1; d <= 15; ++d)
    gru_dual<<<dim3(64, 16), 512, 0, stream>>>(LP(1, d - 1), LP(0, d), 8, 16, wbfW, fz);
  gru_dual<<<dim3(64, 8), 512, 0, stream>>>(LP(1, 15), LP(1, 15), 8, 8, wbfW, fz);

  // ---- layernorm + final projection ----
  ln_all<<<2048, 256, 0, stream>>>(ls1f, ln_g, ln_b, Ybf);
  if (packWout)
    gemm8<<<1000, 512, 0, stream>>>(Ybf, WoutB, out);
  else
    gemm_big<<<dim3(8, 500), 256, 0, stream>>>(Ybf, Wout, 0, out);
}

// Round 12
// 1029.802 us; speedup vs baseline: 1.0511x; 1.0511x over previous
//
#include <hip/hip_runtime.h>

typedef unsigned short u16;
typedef float f32x4 __attribute__((ext_vector_type(4)));
typedef __bf16 bf16x8 __attribute__((ext_vector_type(8)));
typedef u16 u16x8 __attribute__((ext_vector_type(8)));

#define DEVFN __device__ __forceinline__

// B=8, S=256, V=32000, H=1024, HEADS=8, HD=128, N_HIGH=4, N_LOW=16, RATIO=4
// Block = 16 timesteps; 16 blocks. Row layout R(t,b) = (w*16 + o*4 + g)*8 + b.
// States stored per block-index: state[k] = state after block k-1 (state[0]=0).

DEVFN u16 f2bf(float f) {
  unsigned u = __builtin_bit_cast(unsigned, f);
  unsigned r = u + 0x7FFFu + ((u >> 16) & 1u);   // RNE
  return (u16)(r >> 16);
}

DEVFN bf16x8 cvt8(const float* p) {
  float4 f0 = *reinterpret_cast<const float4*>(p);
  float4 f1 = *reinterpret_cast<const float4*>(p + 4);
  u16x8 u;
  u[0] = f2bf(f0.x); u[1] = f2bf(f0.y); u[2] = f2bf(f0.z); u[3] = f2bf(f0.w);
  u[4] = f2bf(f1.x); u[5] = f2bf(f1.y); u[6] = f2bf(f1.z); u[7] = f2bf(f1.w);
  return __builtin_bit_cast(bf16x8, u);
}

DEVFN bf16x8 ldbf(const u16* p) { return *reinterpret_cast<const bf16x8*>(p); }
DEVFN float sigm(float x) { return 1.f / (1.f + expf(-x)); }

DEVFN void gload16(const u16* g, u16* l) {
  __builtin_amdgcn_global_load_lds(
      (const __attribute__((address_space(1))) void*)g,
      (__attribute__((address_space(3))) void*)l, 16, 0, 0);
}

// ============ 256x256 8-phase GEMM for the final projection ========================
// OUT[2048][32000] = A[2048][1024](bf16) @ W[32000][1024](bf16)^T.
// 512 thr = 8 waves (2M x 4N), per-wave C = 128x64. BK=64, 2 LDS buffers (128 KB).
// LDS swizzle: rows are 128B = 8 slots of 16B; slot s of row r holds global slot
// s ^ (r&7); quarter-wave reads hit all 8 slots with 2 lanes/slot (free, m136).
__global__ __launch_bounds__(512) void gemm8(const u16* __restrict__ A,
                                             const u16* __restrict__ W,
                                             float* __restrict__ OUT) {
  __shared__ u16 sm[65536];                       // [buf 2][op 2][16384 elems]

  int nwg = gridDim.x;                            // 1000 (divisible by 8)
  int orig = blockIdx.x;
  int q = nwg >> 3;
  int xcd = orig & 7, idx = orig >> 3;
  int wg = xcd * q + idx;
  int m0 = (wg & 7) * 256;                        // m-fastest: W-panel per XCD
  int n0 = (wg >> 3) * 256;

  int tid = threadIdx.x;
  int wid = tid >> 6, lane = tid & 63;
  int wr = wid >> 2, wc = wid & 3;
  int lr = lane & 15;

  const u16* Abase = A + (size_t)m0 * 1024;
  const u16* Wbase = W + (size_t)n0 * 1024;

  int r0 = tid >> 3;                              // 0..63
  int c0 = ((tid & 7) ^ (r0 & 7)) << 3;           // pre-swizzled source col

  auto STAGE = [&](int half, int ktn, int tb) {   // half: 0=Ah0 1=Ah1 2=Bh0 3=Bh1
    int op = half >> 1, hh = half & 1;
    const u16* gb = op ? Wbase : Abase;
    u16* lp = sm + tb * 32768 + op * 16384 + hh * 8192;
    gload16(gb + (size_t)(hh * 128 + r0) * 1024 + ktn * 64 + c0, lp + tid * 8);
    gload16(gb + (size_t)(hh * 128 + 64 + r0) * 1024 + ktn * 64 + c0, lp + 4096 + tid * 8);
  };

  int aoff[8][2], boff[4][2];
#pragma unroll
  for (int mi = 0; mi < 8; ++mi)
#pragma unroll
    for (int kk = 0; kk < 2; ++kk) {
      int row = mi * 16 + lr;
      int colk = kk * 64 + ((lane >> 4) << 4);
      aoff[mi][kk] = wr * 16384 + row * 128 + (colk ^ ((row & 7) << 4));
    }
#pragma unroll
  for (int ni = 0; ni < 4; ++ni)
#pragma unroll
    for (int kk = 0; kk < 2; ++kk) {
      int rowb = (wc & 1) * 64 + ni * 16 + lr;
      int colk = kk * 64 + ((lane >> 4) << 4);
      boff[ni][kk] = 32768 + (wc >> 1) * 16384 + rowb * 128 +
                     (colk ^ ((rowb & 7) << 4));
    }
  const char* base = (const char*)sm;

  f32x4 acc[8][4];
#pragma unroll
  for (int mi = 0; mi < 8; ++mi)
#pragma unroll
    for (int ni = 0; ni < 4; ++ni) acc[mi][ni] = f32x4{0.f, 0.f, 0.f, 0.f};

  STAGE(0, 0, 0); STAGE(1, 0, 0); STAGE(2, 0, 0); STAGE(3, 0, 0);

  for (int kt = 0; kt < 16; ++kt) {
    int buf = kt & 1;
    int bb = buf * 65536;
    bf16x8 bfr[4][2];
#pragma unroll
    for (int p = 0; p < 4; ++p) {
      if (kt < 15) STAGE(p, kt + 1, buf ^ 1);
      if (p == 0) {
        if (kt < 15) asm volatile("s_waitcnt vmcnt(2)" ::: "memory");
        else         asm volatile("s_waitcnt vmcnt(0)" ::: "memory");
      }
      __builtin_amdgcn_s_barrier();
      asm volatile("" ::: "memory");
      if (p == 0) {
#pragma unroll
        for (int ni = 0; ni < 4; ++ni)
#pragma unroll
          for (int kk = 0; kk < 2; ++kk)
            bfr[ni][kk] = *(const bf16x8*)(base + bb + boff[ni][kk]);
      }
      bf16x8 af[2][2];
#pragma unroll
      for (int dm = 0; dm < 2; ++dm)
#pragma unroll
        for (int kk = 0; kk < 2; ++kk)
          af[dm][kk] = *(const bf16x8*)(base + bb + aoff[p * 2 + dm][kk]);
      __builtin_amdgcn_s_setprio(1);
#pragma unroll
      for (int dm = 0; dm < 2; ++dm)
#pragma unroll
        for (int ni = 0; ni < 4; ++ni)
#pragma unroll
          for (int kk = 0; kk < 2; ++kk)
            acc[p * 2 + dm][ni] = __builtin_amdgcn_mfma_f32_16x16x32_bf16(
                af[dm][kk], bfr[ni][kk], acc[p * 2 + dm][ni], 0, 0, 0);
      __builtin_amdgcn_s_setprio(0);
      __builtin_amdgcn_s_barrier();
      asm volatile("" ::: "memory");
    }
  }

  int rb = (lane >> 4) << 2;
#pragma unroll
  for (int mi = 0; mi < 8; ++mi)
#pragma unroll
    for (int ni = 0; ni < 4; ++ni)
#pragma unroll
      for (int rr = 0; rr < 4; ++rr) {
        size_t o = (size_t)(m0 + wr * 128 + mi * 16 + rb + rr) * 32000 +
                   (size_t)(n0 + wc * 64 + ni * 16 + lr);
        __builtin_nontemporal_store(acc[mi][ni][rr], &OUT[o]);
      }
}

// ============ LDS-staged 128x128 GEMM, BK=32, 3-stage counted-vmcnt pipeline =======
template<int NTSTORE, int OUTF, int BF16OUT, int CADD>
__global__ __launch_bounds__(256) void gemm_lds(
    const u16* __restrict__ A, const u16* __restrict__ W,
    const float* __restrict__ Cadd,
    float* __restrict__ OUT, u16* __restrict__ OUTbf,
    int ldo, int mtiles) {
  __shared__ u16 smA[3][128 * 32];
  __shared__ u16 smB[3][128 * 32];

  int nwg = gridDim.x;
  int orig = blockIdx.x;
  int q = nwg >> 3, r = nwg & 7;
  int xcd = orig & 7, idx = orig >> 3;
  int wg = (xcd < r ? xcd * (q + 1) : r * (q + 1) + (xcd - r) * q) + idx;
  int m0 = (wg % mtiles) * 128;
  int n0 = (wg / mtiles) * 128;

  int tid = threadIdx.x;
  int wv = tid >> 6, lane = tid & 63;
  int lrow = lane >> 2;
  int gcol = ((lane & 3) ^ ((lrow >> 1) & 3)) << 3;

  const u16* gA = A + (size_t)(m0 + wv * 32 + lrow) * 1024 + gcol;
  const u16* gB = W + (size_t)(n0 + wv * 32 + lrow) * 1024 + gcol;
  u16* lA0 = &smA[0][(wv * 32) * 32];
  u16* lA1 = &smA[0][(wv * 32 + 16) * 32];
  u16* lB0 = &smB[0][(wv * 32) * 32];
  u16* lB1 = &smB[0][(wv * 32 + 16) * 32];
  const int BUFO = 128 * 32;

  f32x4 acc[4][4];
#pragma unroll
  for (int mi = 0; mi < 4; ++mi)
#pragma unroll
    for (int ni = 0; ni < 4; ++ni) acc[mi][ni] = f32x4{0.f, 0.f, 0.f, 0.f};

  int qm = (wv >> 1) * 64, qn = (wv & 1) * 64;
  int lr = lane & 15;
  int kk = (lane >> 4) << 3;

  int offA[4], offB[4];
#pragma unroll
  for (int i = 0; i < 4; ++i) {
    int ra = qm + i * 16 + lr;
    offA[i] = ra * 64 + ((kk ^ (((ra >> 1) & 3) << 3)) << 1);
    int rbw = qn + i * 16 + lr;
    offB[i] = rbw * 64 + ((kk ^ (((rbw >> 1) & 3) << 3)) << 1);
  }
  const char* baseA = (const char*)&smA[0][0];
  const char* baseB = (const char*)&smB[0][0];

  gload16(gA, lA0);
  gload16(gA + 16 * 1024, lA1);
  gload16(gB, lB0);
  gload16(gB + 16 * 1024, lB1);
  gload16(gA + 32, lA0 + BUFO);
  gload16(gA + 16 * 1024 + 32, lA1 + BUFO);
  gload16(gB + 32, lB0 + BUFO);
  gload16(gB + 16 * 1024 + 32, lB1 + BUFO);

  for (int kt = 0; kt < 32; ++kt) {
    int buf = kt % 3;
    __builtin_amdgcn_sched_barrier(0);
    if (kt < 31) asm volatile("s_waitcnt vmcnt(4)" ::: "memory");
    else         asm volatile("s_waitcnt vmcnt(0)" ::: "memory");
    __builtin_amdgcn_s_barrier();
    asm volatile("" ::: "memory");
    if (kt < 30) {
      int k0 = (kt + 2) << 5;
      int bo = ((kt + 2) % 3) * BUFO;
      gload16(gA + k0, lA0 + bo);
      gload16(gA + 16 * 1024 + k0, lA1 + bo);
      gload16(gB + k0, lB0 + bo);
      gload16(gB + 16 * 1024 + k0, lB1 + bo);
    }
    int bb = buf * (BUFO * 2);
    bf16x8 av[4], bv[4];
#pragma unroll
    for (int i = 0; i < 4; ++i) {
      av[i] = *(const bf16x8*)(baseA + bb + offA[i]);
      bv[i] = *(const bf16x8*)(baseB + bb + offB[i]);
    }
#pragma unroll
    for (int mi = 0; mi < 4; ++mi)
#pragma unroll
      for (int ni = 0; ni < 4; ++ni)
        acc[mi][ni] = __builtin_amdgcn_mfma_f32_16x16x32_bf16(av[mi], bv[ni], acc[mi][ni], 0, 0, 0);
  }

  int rb = (lane >> 4) << 2;
#pragma unroll
  for (int mi = 0; mi < 4; ++mi)
#pragma unroll
    for (int ni = 0; ni < 4; ++ni)
#pragma unroll
      for (int rr = 0; rr < 4; ++rr) {
        int row = m0 + qm + mi * 16 + rb + rr;
        int col = n0 + qn + ni * 16 + lr;
        size_t o = (size_t)row * (size_t)ldo + col;
        float v = acc[mi][ni][rr];
        if constexpr (CADD) v += Cadd[o];
        if constexpr (OUTF) {
          if constexpr (NTSTORE) __builtin_nontemporal_store(v, &OUT[o]);
          else OUT[o] = v;
        }
        if constexpr (BF16OUT) OUTbf[o] = f2bf(v);
      }
}

// ---------------- generic GEMM (fallback, fp32-weight capable) ----------------------
template<int MT, int NT, int KW>
__global__ __launch_bounds__(64 * KW) void gemm2(
    const u16* __restrict__ A, int lda,
    const void* __restrict__ Wp, int ldw, int kwoff, int wbf,
    const float* __restrict__ Cadd, int ldc,
    float* __restrict__ OUT, u16* __restrict__ OUTbf, int ldo, int K) {
  int tid = threadIdx.x;
  int kw = tid >> 6;
  int lane = tid & 63;
  int lr = lane & 15;
  int kk = (lane >> 4) << 3;
  int n0 = blockIdx.x * (16 * NT);
  int m0 = blockIdx.y * (16 * MT);
  int KP = K / KW;
  int kb = kw * KP + kk;

  f32x4 acc[MT][NT];
#pragma unroll
  for (int mi = 0; mi < MT; ++mi)
#pragma unroll
    for (int ni = 0; ni < NT; ++ni) acc[mi][ni] = f32x4{0.f, 0.f, 0.f, 0.f};

  const u16* ap[MT];
#pragma unroll
  for (int mi = 0; mi < MT; ++mi) ap[mi] = A + (size_t)(m0 + mi * 16 + lr) * (size_t)lda + kb;

  if (wbf) {
    const u16* wb[NT];
#pragma unroll
    for (int ni = 0; ni < NT; ++ni)
      wb[ni] = (const u16*)Wp + (size_t)(n0 + ni * 16 + lr) * (size_t)ldw + kwoff + kb;
    for (int k0 = 0; k0 < KP; k0 += 32) {
      bf16x8 wv[NT];
#pragma unroll
      for (int ni = 0; ni < NT; ++ni) wv[ni] = ldbf(wb[ni] + k0);
#pragma unroll
      for (int mi = 0; mi < MT; ++mi) {
        bf16x8 a = ldbf(ap[mi] + k0);
#pragma unroll
        for (int ni = 0; ni < NT; ++ni)
          acc[mi][ni] = __builtin_amdgcn_mfma_f32_16x16x32_bf16(a, wv[ni], acc[mi][ni], 0, 0, 0);
      }
    }
  } else {
    const float* wf[NT];
#pragma unroll
    for (int ni = 0; ni < NT; ++ni)
      wf[ni] = (const float*)Wp + (size_t)(n0 + ni * 16 + lr) * (size_t)ldw + kwoff + kb;
    for (int k0 = 0; k0 < KP; k0 += 32) {
      bf16x8 wv[NT];
#pragma unroll
      for (int ni = 0; ni < NT; ++ni) wv[ni] = cvt8(wf[ni] + k0);
#pragma unroll
      for (int mi = 0; mi < MT; ++mi) {
        bf16x8 a = ldbf(ap[mi] + k0);
#pragma unroll
        for (int ni = 0; ni < NT; ++ni)
          acc[mi][ni] = __builtin_amdgcn_mfma_f32_16x16x32_bf16(a, wv[ni], acc[mi][ni], 0, 0, 0);
      }
    }
  }

  if constexpr (KW > 1) {
    __shared__ f32x4 red[KW][MT * NT][64];
#pragma unroll
    for (int mi = 0; mi < MT; ++mi)
#pragma unroll
      for (int ni = 0; ni < NT; ++ni) red[kw][mi * NT + ni][lane] = acc[mi][ni];
    __syncthreads();
    if (kw) return;
    for (int w2 = 1; w2 < KW; ++w2)
#pragma unroll
      for (int mi = 0; mi < MT; ++mi)
#pragma unroll
        for (int ni = 0; ni < NT; ++ni) acc[mi][ni] += red[w2][mi * NT + ni][lane];
  }

  int rb = (lane >> 4) << 2;
#pragma unroll
  for (int mi = 0; mi < MT; ++mi)
#pragma unroll
    for (int ni = 0; ni < NT; ++ni)
#pragma unroll
      for (int rr = 0; rr < 4; ++rr) {
        int row = m0 + mi * 16 + rb + rr;
        int col = n0 + ni * 16 + lr;
        size_t o = (size_t)row * (size_t)ldo + col;
        float v = acc[mi][ni][rr];
        if (Cadd) v += Cadd[(size_t)row * (size_t)ldc + col];
        if (OUT) OUT[o] = v;
        if (OUTbf) OUTbf[o] = f2bf(v);
      }
}

// ---------------- shared GRU layer-step body (bf16 weights; slim when gx) -----------
DEVFN void gru_step_body(const u16* __restrict__ X, const u16* __restrict__ Hb,
                         const float* __restrict__ Hf,
                         const u16* __restrict__ Wih, const u16* __restrict__ Whh,
                         const float* __restrict__ bih, const float* __restrict__ bhh,
                         const float* __restrict__ gx,
                         float* __restrict__ Hof, u16* __restrict__ Hob,
                         u16* __restrict__ hist,
                         int m0, int j0, int kw, int lane,
                         f32x4 (*red)[8][64]) {
  int lr = lane & 15;
  int kk = (lane >> 4) << 3;
  const int KP = 256;
  int kb = kw * KP + kk;

  f32x4 aR[2], aZ[2], aNX[2], aNH[2];
#pragma unroll
  for (int mi = 0; mi < 2; ++mi) {
    aR[mi] = f32x4{0.f, 0.f, 0.f, 0.f};
    aZ[mi] = f32x4{0.f, 0.f, 0.f, 0.f};
    aNX[mi] = f32x4{0.f, 0.f, 0.f, 0.f};
    aNH[mi] = f32x4{0.f, 0.f, 0.f, 0.f};
  }

  const u16* hp[2];
#pragma unroll
  for (int mi = 0; mi < 2; ++mi)
    hp[mi] = Hb + (size_t)(m0 + mi * 16 + lr) * 1024 + kb;

  size_t wro = (size_t)(j0 + lr) * 1024 + kb;
  const u16 *phr = Whh + wro, *phz = Whh + wro + 1048576, *phn = Whh + wro + 2097152;

  if (gx) {
    for (int k0 = 0; k0 < KP; k0 += 32) {
      bf16x8 whr = ldbf(phr + k0), whz = ldbf(phz + k0), whn = ldbf(phn + k0);
#pragma unroll
      for (int mi = 0; mi < 2; ++mi) {
        bf16x8 ah = ldbf(hp[mi] + k0);
        aR[mi] = __builtin_amdgcn_mfma_f32_16x16x32_bf16(ah, whr, aR[mi], 0, 0, 0);
        aZ[mi] = __builtin_amdgcn_mfma_f32_16x16x32_bf16(ah, whz, aZ[mi], 0, 0, 0);
        aNH[mi] = __builtin_amdgcn_mfma_f32_16x16x32_bf16(ah, whn, aNH[mi], 0, 0, 0);
      }
    }
  } else {
    const u16* xp[2];
#pragma unroll
    for (int mi = 0; mi < 2; ++mi)
      xp[mi] = X + (size_t)(m0 + mi * 16 + lr) * 1024 + kb;
    const u16 *pxr = Wih + wro, *pxz = Wih + wro + 1048576, *pxn = Wih + wro + 2097152;
    for (int k0 = 0; k0 < KP; k0 += 32) {
      bf16x8 wxr = ldbf(pxr + k0), wxz = ldbf(pxz + k0), wxn = ldbf(pxn + k0);
      bf16x8 whr = ldbf(phr + k0), whz = ldbf(phz + k0), whn = ldbf(phn + k0);
#pragma unroll
      for (int mi = 0; mi < 2; ++mi) {
        bf16x8 ax = ldbf(xp[mi] + k0);
        bf16x8 ah = ldbf(hp[mi] + k0);
        aR[mi] = __builtin_amdgcn_mfma_f32_16x16x32_bf16(ax, wxr, aR[mi], 0, 0, 0);
        aR[mi] = __builtin_amdgcn_mfma_f32_16x16x32_bf16(ah, whr, aR[mi], 0, 0, 0);
        aZ[mi] = __builtin_amdgcn_mfma_f32_16x16x32_bf16(ax, wxz, aZ[mi], 0, 0, 0);
        aZ[mi] = __builtin_amdgcn_mfma_f32_16x16x32_bf16(ah, whz, aZ[mi], 0, 0, 0);
        aNX[mi] = __builtin_amdgcn_mfma_f32_16x16x32_bf16(ax, wxn, aNX[mi], 0, 0, 0);
        aNH[mi] = __builtin_amdgcn_mfma_f32_16x16x32_bf16(ah, whn, aNH[mi], 0, 0, 0);
      }
    }
  }

#pragma unroll
  for (int mi = 0; mi < 2; ++mi) {
    red[kw][mi * 4 + 0][lane] = aR[mi];
    red[kw][mi * 4 + 1][lane] = aZ[mi];
    red[kw][mi * 4 + 2][lane] = aNX[mi];
    red[kw][mi * 4 + 3][lane] = aNH[mi];
  }
  __syncthreads();
  if (kw == 0) {
    for (int w2 = 1; w2 < 4; ++w2)
#pragma unroll
      for (int mi = 0; mi < 2; ++mi) {
        aR[mi] += red[w2][mi * 4 + 0][lane];
        aZ[mi] += red[w2][mi * 4 + 1][lane];
        aNX[mi] += red[w2][mi * 4 + 2][lane];
        aNH[mi] += red[w2][mi * 4 + 3][lane];
      }
    int c = j0 + lr;
    float br = bih[c] + bhh[c];
    float bz = bih[1024 + c] + bhh[1024 + c];
    float bnx = bih[2048 + c];
    float bnh = bhh[2048 + c];
    int rb = (lane >> 4) << 2;
#pragma unroll
    for (int mi = 0; mi < 2; ++mi)
#pragma unroll
      for (int rr = 0; rr < 4; ++rr) {
        int row = m0 + mi * 16 + rb + rr;
        float gr = 0.f, gz = 0.f, gn = 0.f;
        if (gx) {
          const float* gp = gx + (size_t)row * 3072;
          gr = gp[c]; gz = gp[1024 + c]; gn = gp[2048 + c];
        }
        float r = sigm(gr + aR[mi][rr] + br);
        float z = sigm(gz + aZ[mi][rr] + bz);
        float n = tanhf(gn + aNX[mi][rr] + bnx + r * (aNH[mi][rr] + bnh));
        size_t o = (size_t)row * 1024 + c;
        float hv = (1.f - z) * n + z * Hf[o];
        Hof[o] = hv;
        u16 hb = f2bf(hv);
        Hob[o] = hb;
        if (hist) hist[o] = hb;
      }
  }
}

// ---------------- dual GRU layer + folded fp32->bf16 weight conversion --------------
struct GruP {
  const u16* X; const u16* Hb; const float* Hf;
  const u16* Wbih; const u16* Wbhh;
  const float* Wfih; const float* Wfhh;
  const float* bih; const float* bhh;
  const float* gx;
  float* Hof; u16* Hob; u16* hist;
};
struct FoldSeg { const float* src; u16* dst; };
struct FoldArgs { FoldSeg s[7]; long long pref[8]; long long base; long long total; int nseg; };

__global__ __launch_bounds__(256) void gru_dual(GruP pa, GruP pb, int tiles1,
                                                int tiles_total, int wbf, FoldArgs fa) {
  int yy = (int)blockIdx.y;
  if (yy >= tiles_total) {
    if (fa.total == 0) return;
    long long L = (long long)(yy - tiles_total) * gridDim.x + blockIdx.x;
    long long off = fa.base + L * 2048;
    if (off >= fa.total) return;
    int s = 0;
    while (off >= fa.pref[s + 1]) ++s;
    long long local = off - fa.pref[s] + ((long long)threadIdx.x << 3);
    *reinterpret_cast<u16x8*>(fa.s[s].dst + local) =
        __builtin_bit_cast(u16x8, cvt8(fa.s[s].src + local));
    return;
  }

  GruP p; int m0;
  if (yy < tiles1) { p = pa; m0 = yy * 32; }
  else { p = pb; m0 = (yy - tiles1) * 32; }
  int tid = threadIdx.x;
  int kw = tid >> 6;
  int lane = tid & 63;
  __shared__ f32x4 red[4][8][64];
  int j0 = blockIdx.x * 16;

  if (wbf) {
    gru_step_body(p.X, p.Hb, p.Hf, p.Wbih, p.Wbhh, p.bih, p.bhh, p.gx,
                  p.Hof, p.Hob, p.hist, m0, j0, kw, lane, red);
    return;
  }

  // fp32-weight fallback path
  int lr = lane & 15;
  int kk = (lane >> 4) << 3;
  const int KP = 256;
  int kb = kw * KP + kk;
  f32x4 aR[2], aZ[2], aNX[2], aNH[2];
#pragma unroll
  for (int mi = 0; mi < 2; ++mi) {
    aR[mi] = f32x4{0.f, 0.f, 0.f, 0.f};
    aZ[mi] = f32x4{0.f, 0.f, 0.f, 0.f};
    aNX[mi] = f32x4{0.f, 0.f, 0.f, 0.f};
    aNH[mi] = f32x4{0.f, 0.f, 0.f, 0.f};
  }
  const u16* xp[2];
  const u16* hp[2];
#pragma unroll
  for (int mi = 0; mi < 2; ++mi) {
    size_t ro = (size_t)(m0 + mi * 16 + lr) * 1024 + kb;
    xp[mi] = p.X + ro;
    hp[mi] = p.Hb + ro;
  }
  size_t wro = (size_t)(j0 + lr) * 1024 + kb;
  const float *pxr = p.Wfih + wro, *pxz = p.Wfih + wro + 1048576, *pxn = p.Wfih + wro + 2097152;
  const float *phr = p.Wfhh + wro, *phz = p.Wfhh + wro + 1048576, *phn = p.Wfhh + wro + 2097152;
  for (int k0 = 0; k0 < KP; k0 += 32) {
    bf16x8 wxr = cvt8(pxr + k0), wxz = cvt8(pxz + k0), wxn = cvt8(pxn + k0);
    bf16x8 whr = cvt8(phr + k0), whz = cvt8(phz + k0), whn = cvt8(phn + k0);
#pragma unroll
    for (int mi = 0; mi < 2; ++mi) {
      bf16x8 ax = ldbf(xp[mi] + k0);
      bf16x8 ah = ldbf(hp[mi] + k0);
      aR[mi] = __builtin_amdgcn_mfma_f32_16x16x32_bf16(ax, wxr, aR[mi], 0, 0, 0);
      aR[mi] = __builtin_amdgcn_mfma_f32_16x16x32_bf16(ah, whr, aR[mi], 0, 0, 0);
      aZ[mi] = __builtin_amdgcn_mfma_f32_16x16x32_bf16(ax, wxz, aZ[mi], 0, 0, 0);
      aZ[mi] = __builtin_amdgcn_mfma_f32_16x16x32_bf16(ah, whz, aZ[mi], 0, 0, 0);
      aNX[mi] = __builtin_amdgcn_mfma_f32_16x16x32_bf16(ax, wxn, aNX[mi], 0, 0, 0);
      aNH[mi] = __builtin_amdgcn_mfma_f32_16x16x32_bf16(ah, whn, aNH[mi], 0, 0, 0);
    }
  }
#pragma unroll
  for (int mi = 0; mi < 2; ++mi) {
    red[kw][mi * 4 + 0][lane] = aR[mi];
    red[kw][mi * 4 + 1][lane] = aZ[mi];
    red[kw][mi * 4 + 2][lane] = aNX[mi];
    red[kw][mi * 4 + 3][lane] = aNH[mi];
  }
  __syncthreads();
  if (kw) return;
  for (int w2 = 1; w2 < 4; ++w2)
#pragma unroll
    for (int mi = 0; mi < 2; ++mi) {
      aR[mi] += red[w2][mi * 4 + 0][lane];
      aZ[mi] += red[w2][mi * 4 + 1][lane];
      aNX[mi] += red[w2][mi * 4 + 2][lane];
      aNH[mi] += red[w2][mi * 4 + 3][lane];
    }
  int c = j0 + lr;
  float br = p.bih[c] + p.bhh[c];
  float bz = p.bih[1024 + c] + p.bhh[1024 + c];
  float bnx = p.bih[2048 + c];
  float bnh = p.bhh[2048 + c];
  int rb = (lane >> 4) << 2;
#pragma unroll
  for (int mi = 0; mi < 2; ++mi)
#pragma unroll
    for (int rr = 0; rr < 4; ++rr) {
      int row = m0 + mi * 16 + rb + rr;
      float r = sigm(aR[mi][rr] + br);
      float z = sigm(aZ[mi][rr] + bz);
      float n = tanhf(aNX[mi][rr] + bnx + r * (aNH[mi][rr] + bnh));
      size_t o = (size_t)row * 1024 + c;
      float hv = (1.f - z) * n + z * p.Hf[o];
      p.Hof[o] = hv;
      u16 hb = f2bf(hv);
      p.Hob[o] = hb;
      if (p.hist) p.hist[o] = hb;
    }
}

// ---------------- final projection fallback (fp32 W, direct) ------------------------
__global__ __launch_bounds__(256) void gemm_big(const u16* __restrict__ A,
                                                const void* __restrict__ Wp, int wbf,
                                                float* __restrict__ OUT) {
  int wv = threadIdx.x >> 6;
  int lane = threadIdx.x & 63;
  int lr = lane & 15;
  int kk = (lane >> 4) << 3;
  int m0 = blockIdx.x * 256 + wv * 64;
  int n0 = blockIdx.y * 64;

  f32x4 acc[4][4];
#pragma unroll
  for (int mi = 0; mi < 4; ++mi)
#pragma unroll
    for (int ni = 0; ni < 4; ++ni) acc[mi][ni] = f32x4{0.f, 0.f, 0.f, 0.f};

  const u16* ap[4];
#pragma unroll
  for (int mi = 0; mi < 4; ++mi) ap[mi] = A + (size_t)(m0 + mi * 16 + lr) * 1024 + kk;

  const float* wf[4];
#pragma unroll
  for (int ni = 0; ni < 4; ++ni) wf[ni] = (const float*)Wp + (size_t)(n0 + ni * 16 + lr) * 1024 + kk;
  for (int k0 = 0; k0 < 1024; k0 += 32) {
    bf16x8 wvv[4];
#pragma unroll
    for (int ni = 0; ni < 4; ++ni) wvv[ni] = cvt8(wf[ni] + k0);
#pragma unroll
    for (int mi = 0; mi < 4; ++mi) {
      bf16x8 a = ldbf(ap[mi] + k0);
#pragma unroll
      for (int ni = 0; ni < 4; ++ni)
        acc[mi][ni] = __builtin_amdgcn_mfma_f32_16x16x32_bf16(a, wvv[ni], acc[mi][ni], 0, 0, 0);
    }
  }

  int rb = (lane >> 4) << 2;
#pragma unroll
  for (int mi = 0; mi < 4; ++mi)
#pragma unroll
    for (int ni = 0; ni < 4; ++ni)
#pragma unroll
      for (int rr = 0; rr < 4; ++rr) {
        size_t o = (size_t)(m0 + mi * 16 + rb + rr) * 32000 + (size_t)(n0 + ni * 16 + lr);
        __builtin_nontemporal_store(acc[mi][ni][rr], &OUT[o]);
      }
}

// ---------------- fused fp32 -> bf16 weight pack (strided-capable, serial) ----------
struct CvtSeg { const float* src; u16* dst; int src_ld; int col_off; int log2c; int nblk; };
struct CvtArgs { CvtSeg seg[11]; int nseg; };

__global__ void cvt_all(CvtArgs a) {
  int blk = blockIdx.x;
  int s = 0;
  while (s < a.nseg - 1 && blk >= a.seg[s].nblk) { blk -= a.seg[s].nblk; ++s; }
  const CvtSeg g = a.seg[s];
  size_t idx = ((size_t)blk * 256 + threadIdx.x) * 8;
  size_t row = idx >> g.log2c;
  int col = (int)(idx & ((1u << g.log2c) - 1));
  const float* sp = g.src + row * (size_t)g.src_ld + g.col_off + col;
  *reinterpret_cast<u16x8*>(g.dst + idx) = __builtin_bit_cast(u16x8, cvt8(sp));
}

// ---------------- single-dispatch state zeroing -------------------------------------
struct ZeroArgs { unsigned* p[8]; long long pref[9]; };
__global__ void zero8(ZeroArgs z) {
  long long i = (long long)blockIdx.x * 256 + threadIdx.x;
  if (i >= z.pref[8]) return;
  int s = 0;
  while (i >= z.pref[s + 1]) ++s;
  z.p[s][i - z.pref[s]] = 0u;
}

// ---------------- embeds (bf16) + compact high-row copy -----------------------------
__global__ void embed_kernel(const int* __restrict__ ids, const float* __restrict__ emb,
                             const float* __restrict__ pos, u16* __restrict__ out,
                             u16* __restrict__ hiX) {
  int idx = blockIdx.x * 256 + threadIdx.x;
  int e8 = (idx & 127) << 3;
  int rb = idx >> 7;
  int t = rb >> 3, b = rb & 7;
  int w = t >> 4, lsp = t & 15, g = lsp >> 2, o = lsp & 3;
  int R = ((w << 4) + (o << 2) + g) * 8 + b;
  int tok = ids[b * 256 + t];
  const float* ep = emb + (size_t)tok * 1024 + e8;
  const float* pp = pos + (size_t)t * 1024 + e8;
  u16x8 u;
#pragma unroll
  for (int i = 0; i < 8; ++i) u[i] = f2bf(ep[i] + pp[i]);
  *reinterpret_cast<u16x8*>(out + (size_t)R * 1024 + e8) = u;
  if (o == 0)
    *reinterpret_cast<u16x8*>(hiX + (size_t)(w * 32 + g * 8 + b) * 1024 + e8) = u;
}

// ---------------- batched inp = gelu(einp + hc + bin) -------------------------------
__global__ void inp_all(const float* __restrict__ einp, const float* __restrict__ kvhAll,
                        const float* __restrict__ bin, float* __restrict__ inpb,
                        u16* __restrict__ inpbf) {
  int idx = blockIdx.x * 256 + threadIdx.x;
  int r = idx >> 10, j = idx & 1023;
  int w = r >> 7, r7 = r & 127;
  int g = (r7 >> 3) & 3, b = r7 & 7;
  float x = einp[idx] + kvhAll[(size_t)(w * 32 + g * 8 + b) * 3072 + 2048 + j] + bin[j];
  float t = tanhf(0.7978845608028654f * (x + 0.044715f * x * x * x));
  float v = 0.5f * x * (1.f + t);
  inpb[idx] = v;
  inpbf[idx] = f2bf(v);
}

// ---------------- batched attention -------------------------------------------------
__global__ void attn_all(const float* __restrict__ qb, const float* __restrict__ kvhAll,
                         u16* __restrict__ ctxbf) {
  int r = blockIdx.x;
  int w = r >> 7, r7 = r & 127;
  int sp = r7 >> 3;
  int g = sp & 3;
  int b = r7 & 7;
  int lane = threadIdx.x;
  const float* kvb = kvhAll + (size_t)w * 32 * 3072;
  __shared__ float aw[8][4];
  if (lane < 32) {
    int head = lane >> 2, t = lane & 3;
    float s = 0.f;
    if (t <= g) {
      const float* qp = qb + (size_t)r * 1024 + head * 128;
      const float* kp = kvb + (size_t)(t * 8 + b) * 3072 + head * 128;
      for (int d = 0; d < 128; ++d) s += qp[d] * kp[d];
      s *= 0.08838834764831845f;
    }
    float sc[4];
    sc[0] = __shfl(s, (head << 2) + 0);
    sc[1] = __shfl(s, (head << 2) + 1);
    sc[2] = __shfl(s, (head << 2) + 2);
    sc[3] = __shfl(s, (head << 2) + 3);
    if (t == 0) {
      float mx = -1e30f;
      for (int u = 0; u <= g; ++u) mx = fmaxf(mx, sc[u]);
      float p[4] = {0.f, 0.f, 0.f, 0.f};
      float den = 0.f;
      for (int u = 0; u <= g; ++u) { p[u] = expf(sc[u] - mx); den += p[u]; }
      float inv = 1.f / den;
      for (int u = 0; u < 4; ++u) aw[head][u] = (u <= g) ? p[u] * inv : 0.f;
    }
  }
  __syncthreads();
  for (int idx = lane; idx < 1024; idx += 64) {
    int head = idx >> 7;
    float acc = 0.f;
#pragma unroll
    for (int t = 0; t < 4; ++t) acc += aw[head][t] * kvb[(size_t)(t * 8 + b) * 3072 + 1024 + idx];
    ctxbf[(size_t)r * 1024 + idx] = f2bf(acc);
  }
}

// ---------------- batched layernorm -> bf16 Y ---------------------------------------
__global__ void ln_all(const float* __restrict__ ls1f, const float* __restrict__ g_,
                       const float* __restrict__ b_, u16* __restrict__ Ybf) {
  int bid = blockIdx.x;
  int w = bid >> 7, r7 = bid & 127;
  int tid = threadIdx.x;
  const float* x = ls1f + (size_t)(w + 1) * 131072 + (size_t)r7 * 1024;
  float s = 0.f, s2 = 0.f;
  for (int j = tid; j < 1024; j += 256) { float v = x[j]; s += v; s2 += v * v; }
  for (int off = 32; off; off >>= 1) { s += __shfl_xor(s, off); s2 += __shfl_xor(s2, off); }
  __shared__ float rs[4], rs2[4], mv[2];
  int wv = tid >> 6;
  if ((tid & 63) == 0) { rs[wv] = s; rs2[wv] = s2; }
  __syncthreads();
  if (tid == 0) {
    float S = rs[0] + rs[1] + rs[2] + rs[3];
    float S2 = rs2[0] + rs2[1] + rs2[2] + rs2[3];
    float mu = S * (1.f / 1024.f);
    float var = S2 * (1.f / 1024.f) - mu * mu;
    mv[0] = mu;
    mv[1] = rsqrtf(var + 1e-5f);
  }
  __syncthreads();
  float mu = mv[0], rstd = mv[1];
  int sp = r7 >> 3, b = r7 & 7;
  int g = sp & 3, o = sp >> 2;
  int t = w * 16 + g * 4 + o;
  u16* yrow = Ybf + (size_t)(b * 256 + t) * 1024;
  for (int j = tid; j < 1024; j += 256) {
    float v = (x[j] - mu) * rstd * g_[j] + b_[j];
    yrow[j] = f2bf(v);
  }
}

extern "C" void kernel_launch(void* const* d_in, const int* in_sizes, int n_in,
                              void* d_out, int out_size, void* d_ws, size_t ws_size,
                              hipStream_t stream) {
  const int* ids = (const int*)d_in[0];
  const float* emb = (const float*)d_in[1];
  const float* pos = (const float*)d_in[2];
  const float* Wih_h = (const float*)d_in[3];
  const float* bih_h = (const float*)d_in[4];
  const float* Whh_h = (const float*)d_in[5];
  const float* bhh_h = (const float*)d_in[6];
  const float* Win = (const float*)d_in[7];
  const float* bin_ = (const float*)d_in[8];
  const float* Wq = (const float*)d_in[9];
  const float* Wk = (const float*)d_in[10];
  const float* Wv = (const float*)d_in[11];
  const float* Wo = (const float*)d_in[12];
  const float* Wih_l = (const float*)d_in[13];
  const float* bih_l = (const float*)d_in[14];
  const float* Whh_l = (const float*)d_in[15];
  const float* bhh_l = (const float*)d_in[16];
  const float* ln_g = (const float*)d_in[17];
  const float* ln_b = (const float*)d_in[18];
  const float* Wout = (const float*)d_in[19];
  float* out = (float*)d_out;

  size_t off = 0;
  char* wsb = (char*)d_ws;
  auto allocF = [&](size_t n) { float* p = (float*)(wsb + off); off += n * 4; return p; };
  auto allocU = [&](size_t n) { u16* p = (u16*)(wsb + off); off += n * 2; return p; };

  float* hs0f = allocF((size_t)17 * 32768);
  float* hs1f = allocF((size_t)17 * 32768);
  float* ls0f = allocF((size_t)17 * 131072);
  float* ls1f = allocF((size_t)17 * 131072);
  u16* hs0b = allocU((size_t)17 * 32768);
  u16* hs1b = allocU((size_t)17 * 32768);
  u16* ls0b = allocU((size_t)17 * 131072);
  u16* ls1b = allocU((size_t)17 * 131072);
  u16* histAll = allocU(524288);
  u16* embB = allocU(2097152);
  u16* hiX = allocU(524288);              // [512][1024] compact high rows
  float* einp = allocF(2097152);
  float* kvhAll = allocF((size_t)512 * 3072);
  float* inpb = allocF(2097152);
  u16* inpbf = allocU(2097152);
  float* qb = allocF(2097152);
  u16* ctxbf = allocU(2097152);
  u16* x2bf = allocU(2097152);
  u16* Ybf = allocU(2097152);
  float* GXH = allocF((size_t)512 * 3072);    // high l0 x-gates
  float* GXL = allocF((size_t)2048 * 3072);   // low l0 x-gates

  const size_t WPACK_BYTES = (size_t)(4 * 6291456 + 1048576 + 1048576 + 1048576 + 3145728) * 2;
  bool packW = (off + WPACK_BYTES <= ws_size);
  u16 *WihHb = nullptr, *WhhHb = nullptr, *WihLb = nullptr, *WhhLb = nullptr;
  u16 *WinB0 = nullptr, *WqB = nullptr, *WoB = nullptr, *KVp = nullptr;
  if (packW) {
    WihHb = allocU(6291456);
    WhhHb = allocU(6291456);
    WihLb = allocU(6291456);
    WhhLb = allocU(6291456);
    WinB0 = allocU(1048576);
    WqB = allocU(1048576);
    WoB = allocU(1048576);
    KVp = allocU(3145728);
  }
  bool packWout = packW && (off + (size_t)32768000 * 2 <= ws_size);
  u16* WoutB = nullptr;
  if (packWout) WoutB = allocU(32768000);

  // ---- single-dispatch zero of all 8 state slice-0 regions ----
  {
    ZeroArgs z;
    long long pf = 0;
    int si = 0;
    auto addZ = [&](void* p, long long words) {
      z.p[si] = (unsigned*)p; z.pref[si] = pf; pf += words; ++si;
    };
    addZ(hs0f, 32768); addZ(hs1f, 32768); addZ(ls0f, 131072); addZ(ls1f, 131072);
    addZ(hs0b, 16384); addZ(hs1b, 16384); addZ(ls0b, 65536); addZ(ls1b, 65536);
    z.pref[8] = pf;     // 491520 words
    zero8<<<(int)((pf + 255) / 256), 256, 0, stream>>>(z);
  }

  // ---- prologue ----
  embed_kernel<<<1024, 256, 0, stream>>>(ids, emb, pos, embB, hiX);
  if (packW) {
    CvtArgs ca{};
    int ns = 0, tot = 0;
    auto add = [&](const float* s, u16* d, int ld, int co, int l2c, size_t nelem) {
      int nb = (int)(nelem / 2048);
      ca.seg[ns++] = CvtSeg{s, d, ld, co, l2c, nb};
      tot += nb;
    };
    add(Wih_h, WihHb, 1024, 0, 10, 6291456);
    add(Whh_h, WhhHb, 1024, 0, 10, 6291456);
    add(Win, WinB0, 2048, 0, 10, 1048576);
    add(Win, KVp + 2097152, 2048, 1024, 10, 1048576);
    ca.nseg = ns;
    cvt_all<<<tot, 256, 0, stream>>>(ca);
  }
  int wbfW = packW ? 1 : 0;

  // folded flat conversions distributed across the 17 high-chain dispatches
  FoldArgs fa{};
  fa.total = 0;
  FoldArgs fz{};
  fz.total = 0;
  long long bpd = 0;
  int extraY = 0;
  if (packW) {
    int ns = 0;
    long long pref = 0;
    auto addF = [&](const float* s, u16* d, long long n) {
      fa.s[ns].src = s; fa.s[ns].dst = d; fa.pref[ns] = pref; pref += n; ++ns;
    };
    addF(Wih_l, WihLb, 6291456);
    addF(Whh_l, WhhLb, 6291456);
    addF(Wq, WqB, 1048576);
    addF(Wo, WoB, 1048576);
    addF(Wk, KVp, 1048576);
    addF(Wv, KVp + 1048576, 1048576);
    if (packWout) addF(Wout, WoutB, 32768000);
    fa.pref[ns] = pref;
    fa.total = pref;
    fa.nseg = ns;
    long long tb = pref / 2048;
    bpd = (tb + 16) / 17;
    extraY = (int)((bpd + 63) / 64);
  }

  // einp + high l0 x-gates (batched)
  if (packW) {
    gemm_lds<0, 1, 0, 0><<<128, 256, 0, stream>>>(embB, WinB0, nullptr, einp, nullptr, 1024, 16);
    gemm_lds<0, 1, 0, 0><<<96, 256, 0, stream>>>(hiX, WihHb, nullptr, GXH, nullptr, 3072, 4);
  } else {
    gemm2<2, 2, 2><<<dim3(32, 64), 128, 0, stream>>>(
        embB, 1024, Win, 2048, 0, 0, nullptr, 0, einp, nullptr, 1024, 1024);
  }

  const size_t LW = (size_t)3072 * 1024;
  auto HP = [&](int layer, int w) {
    GruP p;
    if (layer == 0) {
      p.X = embB + (size_t)w * 131072;
      p.Hb = hs0b + (size_t)w * 32768; p.Hf = hs0f + (size_t)w * 32768;
      p.Wbih = WihHb; p.Wbhh = WhhHb; p.Wfih = Wih_h; p.Wfhh = Whh_h;
      p.bih = bih_h; p.bhh = bhh_h;
      p.gx = packW ? (GXH + (size_t)w * 32 * 3072) : nullptr;
      p.Hof = hs0f + (size_t)(w + 1) * 32768; p.Hob = hs0b + (size_t)(w + 1) * 32768;
      p.hist = nullptr;
    } else {
      p.X = hs0b + (size_t)(w + 1) * 32768;
      p.Hb = hs1b + (size_t)w * 32768; p.Hf = hs1f + (size_t)w * 32768;
      p.Wbih = WihHb ? WihHb + LW : nullptr; p.Wbhh = WhhHb ? WhhHb + LW : nullptr;
      p.Wfih = Wih_h + LW; p.Wfhh = Whh_h + LW;
      p.bih = bih_h + 3072; p.bhh = bhh_h + 3072;
      p.gx = nullptr;
      p.Hof = hs1f + (size_t)(w + 1) * 32768; p.Hob = hs1b + (size_t)(w + 1) * 32768;
      p.hist = histAll + (size_t)w * 32768;
    }
    return p;
  };
  auto LP = [&](int layer, int w) {
    GruP p;
    if (layer == 0) {
      p.X = x2bf + (size_t)w * 131072;
      p.Hb = ls0b + (size_t)w * 131072; p.Hf = ls0f + (size_t)w * 131072;
      p.Wbih = WihLb; p.Wbhh = WhhLb; p.Wfih = Wih_l; p.Wfhh = Whh_l;
      p.bih = bih_l; p.bhh = bhh_l;
      p.gx = packW ? (GXL + (size_t)w * 128 * 3072) : nullptr;
      p.Hof = ls0f + (size_t)(w + 1) * 131072; p.Hob = ls0b + (size_t)(w + 1) * 131072;
      p.hist = nullptr;
    } else {
      p.X = ls0b + (size_t)(w + 1) * 131072;
      p.Hb = ls1b + (size_t)w * 131072; p.Hf = ls1f + (size_t)w * 131072;
      p.Wbih = WihLb ? WihLb + LW : nullptr; p.Wbhh = WhhLb ? WhhLb + LW : nullptr;
      p.Wfih = Wih_l + LW; p.Wfhh = Whh_l + LW;
      p.bih = bih_l + 3072; p.bhh = bhh_l + 3072;
      p.gx = nullptr;
      p.Hof = ls1f + (size_t)(w + 1) * 131072; p.Hob = ls1b + (size_t)(w + 1) * 131072;
      p.hist = nullptr;
    }
    return p;
  };

  // ---- high chain: 17 dispatches (+folded cvt on idle CUs) ----
  auto launch_high = [&](GruP pa, GruP pb, int t1, int ttot, int d) {
    if (packW && fa.total) {
      fa.base = (long long)d * bpd * 2048;
      gru_dual<<<dim3(64, ttot + extraY), 256, 0, stream>>>(pa, pb, t1, ttot, wbfW, fa);
    } else {
      gru_dual<<<dim3(64, ttot), 256, 0, stream>>>(pa, pb, t1, ttot, wbfW, fz);
    }
  };
  launch_high(HP(0, 0), HP(0, 0), 1, 1, 0);
  for (int d = 1; d <= 15; ++d) launch_high(HP(1, d - 1), HP(0, d), 1, 2, d);
  launch_high(HP(1, 15), HP(1, 15), 1, 1, 16);

  // ---- batched mid-section ----
  if (packW) {
    gemm_lds<0, 1, 0, 0><<<96, 256, 0, stream>>>(histAll, KVp, nullptr, kvhAll, nullptr, 3072, 4);
  } else {
    gemm2<2, 2, 2><<<dim3(32, 16), 128, 0, stream>>>(
        histAll, 1024, Wk, 1024, 0, 0, nullptr, 0, kvhAll, nullptr, 3072, 1024);
    gemm2<2, 2, 2><<<dim3(32, 16), 128, 0, stream>>>(
        histAll, 1024, Wv, 1024, 0, 0, nullptr, 0, kvhAll + 1024, nullptr, 3072, 1024);
    gemm2<2, 2, 2><<<dim3(32, 16), 128, 0, stream>>>(
        histAll, 1024, Win, 2048, 1024, 0, nullptr, 0, kvhAll + 2048, nullptr, 3072, 1024);
  }
  inp_all<<<8192, 256, 0, stream>>>(einp, kvhAll, bin_, inpb, inpbf);
  if (packW)
    gemm_lds<0, 1, 0, 0><<<128, 256, 0, stream>>>(inpbf, WqB, nullptr, qb, nullptr, 1024, 16);
  else
    gemm2<2, 2, 2><<<dim3(32, 64), 128, 0, stream>>>(
        inpbf, 1024, Wq, 1024, 0, 0, nullptr, 0, qb, nullptr, 1024, 1024);
  attn_all<<<2048, 64, 0, stream>>>(qb, kvhAll, ctxbf);
  if (packW) {
    gemm_lds<0, 0, 1, 1><<<128, 256, 0, stream>>>(ctxbf, WoB, inpb, nullptr, x2bf, 1024, 16);
    gemm_lds<0, 1, 0, 0><<<384, 256, 0, stream>>>(x2bf, WihLb, nullptr, GXL, nullptr, 3072, 16);
  } else {
    gemm2<2, 2, 2><<<dim3(32, 64), 128, 0, stream>>>(
        ctxbf, 1024, Wo, 1024, 0, 0, inpb, 1024, nullptr, x2bf, 1024, 1024);
  }

  // ---- low chain: 17 dispatches (l1(w-1) paired with l0(w)) ----
  gru_dual<<<dim3(64, 4), 256, 0, stream>>>(LP(0, 0), LP(0, 0), 4, 4, wbfW, fz);
  for (int d = 1; d <= 15; ++d)
    gru_dual<<<dim3(64, 8), 256, 0, stream>>>(LP(1, d - 1), LP(0, d), 4, 8, wbfW, fz);
  gru_dual<<<dim3(64, 4), 256, 0, stream>>>(LP(1, 15), LP(1, 15), 4, 4, wbfW, fz);

  // ---- layernorm + final projection ----
  ln_all<<<2048, 256, 0, stream>>>(ls1f, ln_g, ln_b, Ybf);
  if (packWout)
    gemm8<<<1000, 512, 0, stream>>>(Ybf, WoutB, out);
  else
    gemm_big<<<dim3(8, 500), 256, 0, stream>>>(Ybf, Wout, 0, out);
}